// Round 1
// baseline (8742.448 us; speedup 1.0000x reference)
//
#include <hip/hip_runtime.h>
#include <hip/hip_bf16.h>

// ---------------------------------------------------------------------------
// GCN 2-layer: out = Ahat * relu(Ahat * X * W1 + b1) * W2 + b2
// Ahat = D^-1/2 (A+I) D^-1/2, D = in-degree(+1) from dst side.
//
// Decomposition (per call):
//  1) deg[v]   = #incoming edges (atomic u32)            [dst only]
//  2) dinv[v]  = rsqrtf(deg[v]+1)                        (+1 = self loop)
//  3) hs       = (X @ W1) * dinv[row]       (prescaled rows, SGEMM f32)
//  4) t[dst]  += hs[src]  over all edges    (f32 atomics, pull in later rounds)
//  5) h1       = relu((t + hs) * dinv + b1)  -> written in-place into t
//  6) hs2      = (h1 @ W2) * dinv[row]
//  7) t2[dst] += hs2[src]
//  8) out      = (t2 + hs2) * dinv + b2
// ---------------------------------------------------------------------------

__global__ void deg_kernel(const int* __restrict__ dst, int E, unsigned* __restrict__ deg) {
    int stride = gridDim.x * blockDim.x;
    for (int e = blockIdx.x * blockDim.x + threadIdx.x; e < E; e += stride)
        atomicAdd(&deg[dst[e]], 1u);
}

__global__ void dinv_kernel(const unsigned* __restrict__ deg, float* __restrict__ dinv, int N) {
    int v = blockIdx.x * blockDim.x + threadIdx.x;
    if (v < N) dinv[v] = rsqrtf((float)(deg[v] + 1u));
}

// Classic 128xBN LDS-tiled SGEMM, C[row] scaled by dinv[row].
// A: M x K row-major, B: K x BN row-major, C: M x BN.
template <int BN, int K>
__global__ __launch_bounds__(256) void gemm_scale(
    const float* __restrict__ A, const float* __restrict__ B,
    const float* __restrict__ dinv, float* __restrict__ C, int M)
{
    constexpr int BM = 128, BK = 16;
    constexpr int TM = 8, TN = BN / 16;          // 16x16 threads, TMxTN per thread
    __shared__ float As[BK][BM + 4];             // transposed A tile (+pad)
    __shared__ float Bs[BK][BN];

    const int tid = threadIdx.x;
    const int tx = tid & 15, ty = tid >> 4;
    const int brow = blockIdx.x * BM;

    float acc[TM][TN];
    #pragma unroll
    for (int i = 0; i < TM; ++i)
        #pragma unroll
        for (int j = 0; j < TN; ++j) acc[i][j] = 0.f;

    for (int k0 = 0; k0 < K; k0 += BK) {
        // A tile: BM x BK  (512 float4s, 2 per thread)
        #pragma unroll
        for (int i = 0; i < 2; ++i) {
            int idx = tid + i * 256;         // float4 index
            int row = idx >> 2;              // 0..127
            int c4  = (idx & 3) << 2;        // 0,4,8,12
            int gr  = brow + row;
            float4 v = make_float4(0.f, 0.f, 0.f, 0.f);
            if (gr < M) v = *(const float4*)(A + (size_t)gr * K + k0 + c4);
            As[c4 + 0][row] = v.x; As[c4 + 1][row] = v.y;
            As[c4 + 2][row] = v.z; As[c4 + 3][row] = v.w;
        }
        // B tile: BK x BN  (BK*BN/4 float4s, BN/64 per thread)
        #pragma unroll
        for (int i = 0; i < BN / 64; ++i) {
            int idx = tid + i * 256;
            int row = idx / (BN / 4);
            int c4  = (idx % (BN / 4)) << 2;
            *(float4*)&Bs[row][c4] = *(const float4*)(B + (size_t)(k0 + row) * BN + c4);
        }
        __syncthreads();
        #pragma unroll
        for (int k = 0; k < BK; ++k) {
            float a[TM], b[TN];
            #pragma unroll
            for (int i = 0; i < TM; ++i) a[i] = As[k][ty * TM + i];
            #pragma unroll
            for (int j = 0; j < TN; ++j) b[j] = Bs[k][tx * TN + j];
            #pragma unroll
            for (int i = 0; i < TM; ++i)
                #pragma unroll
                for (int j = 0; j < TN; ++j) acc[i][j] = fmaf(a[i], b[j], acc[i][j]);
        }
        __syncthreads();
    }
    #pragma unroll
    for (int i = 0; i < TM; ++i) {
        int gr = brow + ty * TM + i;
        if (gr >= M) continue;
        float s = dinv[gr];
        #pragma unroll
        for (int j = 0; j < TN; j += 4) {
            float4 o;
            o.x = acc[i][j + 0] * s; o.y = acc[i][j + 1] * s;
            o.z = acc[i][j + 2] * s; o.w = acc[i][j + 3] * s;
            *(float4*)(C + (size_t)gr * BN + tx * TN + j) = o;
        }
    }
}

// t[dst] += hs[src], F floats per edge, 4 floats per thread (float4 gather).
template <int LOGF>
__global__ void scatter_kernel(const int* __restrict__ src, const int* __restrict__ dst,
                               const float* __restrict__ hs, float* __restrict__ t, long total4)
{
    constexpr int F4 = 1 << (LOGF - 2);   // float4s per edge row
    long stride = (long)gridDim.x * blockDim.x;
    for (long idx = (long)blockIdx.x * blockDim.x + threadIdx.x; idx < total4; idx += stride) {
        int e  = (int)(idx >> (LOGF - 2));
        int j4 = ((int)idx & (F4 - 1)) << 2;
        int s = src[e], d = dst[e];
        float4 v = *(const float4*)(hs + ((size_t)s << LOGF) + j4);
        float* p = t + ((size_t)d << LOGF) + j4;
        atomicAdd(p + 0, v.x);
        atomicAdd(p + 1, v.y);
        atomicAdd(p + 2, v.z);
        atomicAdd(p + 3, v.w);
    }
}

// out = [relu]((t + hs) * dinv[v] + bias[j]); out may alias t (elementwise).
template <int LOGF, bool RELU>
__global__ void finalize_kernel(const float* __restrict__ t, const float* __restrict__ hs,
                                const float* __restrict__ dinv, const float* __restrict__ bias,
                                float* __restrict__ out, int N)
{
    constexpr int F = 1 << LOGF;
    long total = (long)N * F;
    long stride = (long)gridDim.x * blockDim.x;
    for (long idx = (long)blockIdx.x * blockDim.x + threadIdx.x; idx < total; idx += stride) {
        int v = (int)(idx >> LOGF);
        int j = (int)idx & (F - 1);
        float r = (t[idx] + hs[idx]) * dinv[v] + bias[j];
        out[idx] = RELU ? fmaxf(r, 0.f) : r;
    }
}

extern "C" void kernel_launch(void* const* d_in, const int* in_sizes, int n_in,
                              void* d_out, int out_size, void* d_ws, size_t ws_size,
                              hipStream_t stream)
{
    const float* x  = (const float*)d_in[0];
    const int*   ei = (const int*)d_in[1];
    const float* W1 = (const float*)d_in[2];
    const float* b1 = (const float*)d_in[3];
    const float* W2 = (const float*)d_in[4];
    const float* b2 = (const float*)d_in[5];
    float* out = (float*)d_out;

    const int N = in_sizes[0] / 512;
    const int E = in_sizes[1] / 2;
    const int* src = ei;
    const int* dst = ei + E;

    // workspace layout
    unsigned* deg = (unsigned*)d_ws;                    // N u32
    float* dinv = (float*)(deg + N);                    // N f32
    float* hs   = dinv + N;                             // N*128 f32
    float* tbuf = hs + (size_t)N * 128;                 // N*128 f32
    float* hs2  = hs;                                   // N*64  (reuse after finalize1)
    float* t2   = hs + (size_t)N * 64;                  // N*64

    hipMemsetAsync(deg, 0, (size_t)N * 4, stream);
    hipMemsetAsync(tbuf, 0, (size_t)N * 128 * 4, stream);

    deg_kernel<<<dim3((E + 255) / 256), 256, 0, stream>>>(dst, E, deg);
    dinv_kernel<<<dim3((N + 255) / 256), 256, 0, stream>>>(deg, dinv, N);

    // layer 1
    gemm_scale<128, 512><<<dim3((N + 127) / 128), 256, 0, stream>>>(x, W1, dinv, hs, N);
    scatter_kernel<7><<<dim3(4096), 256, 0, stream>>>(src, dst, hs, tbuf, (long)E * 32);
    finalize_kernel<7, true><<<dim3(2048), 256, 0, stream>>>(tbuf, hs, dinv, b1, tbuf, N);

    // layer 2 (hs region free now; carve hs2 + t2 out of it)
    hipMemsetAsync(t2, 0, (size_t)N * 64 * 4, stream);
    gemm_scale<64, 128><<<dim3((N + 127) / 128), 256, 0, stream>>>(tbuf, W2, dinv, hs2, N);
    scatter_kernel<6><<<dim3(4096), 256, 0, stream>>>(src, dst, hs2, t2, (long)E * 16);
    finalize_kernel<6, false><<<dim3(2048), 256, 0, stream>>>(t2, hs2, dinv, b2, out, N);
}

// Round 2
// 1214.449 us; speedup vs baseline: 7.1987x; 7.1987x over previous
//
#include <hip/hip_runtime.h>
#include <hip/hip_bf16.h>

// ---------------------------------------------------------------------------
// GCN 2-layer, pull-mode:
//   out = Ahat * relu(Ahat * X * W1 + b1) * W2 + b2,  Ahat = D^-1/2 (A+I) D^-1/2
//
// Per call:
//  1) deg[v]  = in-degree (atomic u32)
//  2) dinv[v] = rsqrtf(deg+1)
//  3) CSR by dst: exclusive scan of deg -> off[], then fill csr_src[] (int atomics)
//  4) hs  = (X @ W1) * dinv[row]                      (SGEMM, prescaled rows)
//  5) h1[v] = relu((sum_{s in in(v)} hs[s] + hs[v]) * dinv[v] + b1)   [pull, no atomics]
//  6) hs2 = (h1 @ W2) * dinv[row]
//  7) out[v] = (sum hs2[s] + hs2[v]) * dinv[v] + b2
// ---------------------------------------------------------------------------

__global__ void deg_kernel(const int* __restrict__ dst, int E, unsigned* __restrict__ deg) {
    int stride = gridDim.x * blockDim.x;
    for (int e = blockIdx.x * blockDim.x + threadIdx.x; e < E; e += stride)
        atomicAdd(&deg[dst[e]], 1u);
}

__global__ void dinv_kernel(const unsigned* __restrict__ deg, float* __restrict__ dinv, int N) {
    int v = blockIdx.x * blockDim.x + threadIdx.x;
    if (v < N) dinv[v] = rsqrtf((float)(deg[v] + 1u));
}

// ---- exclusive scan of deg[0..N) -> off[0..N], two-level ----
__global__ void scan_block(const unsigned* __restrict__ deg, int* __restrict__ off,
                           unsigned* __restrict__ partials, int N) {
    __shared__ unsigned s[256];
    int v = blockIdx.x * 256 + threadIdx.x;
    unsigned x = (v < N) ? deg[v] : 0u;
    s[threadIdx.x] = x;
    __syncthreads();
    #pragma unroll
    for (int d = 1; d < 256; d <<= 1) {
        unsigned t = (threadIdx.x >= d) ? s[threadIdx.x - d] : 0u;
        __syncthreads();
        s[threadIdx.x] += t;
        __syncthreads();
    }
    if (v < N) off[v] = (int)(s[threadIdx.x] - x);     // exclusive (local)
    if (threadIdx.x == 255) partials[blockIdx.x] = s[255];
}

__global__ void scan_partials(unsigned* __restrict__ partials, int B) {
    __shared__ unsigned s[1024];
    int i = threadIdx.x;
    unsigned x = (i < B) ? partials[i] : 0u;
    s[i] = x;
    __syncthreads();
    #pragma unroll
    for (int d = 1; d < 1024; d <<= 1) {
        unsigned t = (i >= d) ? s[i - d] : 0u;
        __syncthreads();
        s[i] += t;
        __syncthreads();
    }
    if (i < B) partials[i] = s[i] - x;                 // exclusive
}

__global__ void add_partials(int* __restrict__ off, const unsigned* __restrict__ partials,
                             int N, int E) {
    int v = blockIdx.x * 256 + threadIdx.x;
    if (v < N) off[v] += (int)partials[blockIdx.x];
    if (v == 0) off[N] = E;
}

__global__ void fill_csr(const int* __restrict__ src, const int* __restrict__ dst, int E,
                         const int* __restrict__ off, unsigned* __restrict__ cursor,
                         int* __restrict__ csr) {
    int stride = gridDim.x * blockDim.x;
    for (int e = blockIdx.x * blockDim.x + threadIdx.x; e < E; e += stride) {
        int d = dst[e];
        unsigned p = atomicAdd(&cursor[d], 1u);
        csr[off[d] + (int)p] = src[e];
    }
}

// ---- SGEMM with per-row dinv scale (unchanged from R1) ----
template <int BN, int K>
__global__ __launch_bounds__(256) void gemm_scale(
    const float* __restrict__ A, const float* __restrict__ B,
    const float* __restrict__ dinv, float* __restrict__ C, int M)
{
    constexpr int BM = 128, BK = 16;
    constexpr int TM = 8, TN = BN / 16;
    __shared__ float As[BK][BM + 4];
    __shared__ float Bs[BK][BN];

    const int tid = threadIdx.x;
    const int tx = tid & 15, ty = tid >> 4;
    const int brow = blockIdx.x * BM;

    float acc[TM][TN];
    #pragma unroll
    for (int i = 0; i < TM; ++i)
        #pragma unroll
        for (int j = 0; j < TN; ++j) acc[i][j] = 0.f;

    for (int k0 = 0; k0 < K; k0 += BK) {
        #pragma unroll
        for (int i = 0; i < 2; ++i) {
            int idx = tid + i * 256;
            int row = idx >> 2;
            int c4  = (idx & 3) << 2;
            int gr  = brow + row;
            float4 v = make_float4(0.f, 0.f, 0.f, 0.f);
            if (gr < M) v = *(const float4*)(A + (size_t)gr * K + k0 + c4);
            As[c4 + 0][row] = v.x; As[c4 + 1][row] = v.y;
            As[c4 + 2][row] = v.z; As[c4 + 3][row] = v.w;
        }
        #pragma unroll
        for (int i = 0; i < BN / 64; ++i) {
            int idx = tid + i * 256;
            int row = idx / (BN / 4);
            int c4  = (idx % (BN / 4)) << 2;
            *(float4*)&Bs[row][c4] = *(const float4*)(B + (size_t)(k0 + row) * BN + c4);
        }
        __syncthreads();
        #pragma unroll
        for (int k = 0; k < BK; ++k) {
            float a[TM], b[TN];
            #pragma unroll
            for (int i = 0; i < TM; ++i) a[i] = As[k][ty * TM + i];
            #pragma unroll
            for (int j = 0; j < TN; ++j) b[j] = Bs[k][tx * TN + j];
            #pragma unroll
            for (int i = 0; i < TM; ++i)
                #pragma unroll
                for (int j = 0; j < TN; ++j) acc[i][j] = fmaf(a[i], b[j], acc[i][j]);
        }
        __syncthreads();
    }
    #pragma unroll
    for (int i = 0; i < TM; ++i) {
        int gr = brow + ty * TM + i;
        if (gr >= M) continue;
        float s = dinv[gr];
        #pragma unroll
        for (int j = 0; j < TN; j += 4) {
            float4 o;
            o.x = acc[i][j + 0] * s; o.y = acc[i][j + 1] * s;
            o.z = acc[i][j + 2] * s; o.w = acc[i][j + 3] * s;
            *(float4*)(C + (size_t)gr * BN + tx * TN + j) = o;
        }
    }
}

// ---- pull-mode aggregation, one wave per node, fused epilogue ----
// out[v] = [relu]((sum_{s} hs[s] + hs[v]) * dinv[v] + bias)
template <int F, bool RELU>
__global__ __launch_bounds__(256) void agg_pull(
    const int* __restrict__ off, const int* __restrict__ csr,
    const float* __restrict__ hs, const float* __restrict__ dinv,
    const float* __restrict__ bias, float* __restrict__ out, int N)
{
    constexpr int PER = F / 64;                 // floats per lane (2 or 1)
    const int lane = threadIdx.x & 63;
    const int v = blockIdx.x * (blockDim.x >> 6) + (threadIdx.x >> 6);
    if (v >= N) return;

    const int s0 = off[v], s1 = off[v + 1];
    float acc[PER];
    #pragma unroll
    for (int i = 0; i < PER; ++i) acc[i] = 0.f;

    for (int e0 = s0; e0 < s1; e0 += 64) {
        int nid = (e0 + lane < s1) ? csr[e0 + lane] : 0;
        int cnt = min(64, s1 - e0);
        for (int j = 0; j < cnt; ++j) {
            int s = __shfl(nid, j);
            if (PER == 2) {
                float2 g = *(const float2*)(hs + (size_t)s * F + lane * 2);
                acc[0] += g.x; acc[1] += g.y;
            } else {
                acc[0] += hs[(size_t)s * F + lane];
            }
        }
    }
    // self loop + epilogue
    const float dv = dinv[v];
    if (PER == 2) {
        float2 g = *(const float2*)(hs + (size_t)v * F + lane * 2);
        float r0 = (acc[0] + g.x) * dv + bias[lane * 2 + 0];
        float r1 = (acc[1] + g.y) * dv + bias[lane * 2 + 1];
        if (RELU) { r0 = fmaxf(r0, 0.f); r1 = fmaxf(r1, 0.f); }
        *(float2*)(out + (size_t)v * F + lane * 2) = make_float2(r0, r1);
    } else {
        float r0 = (acc[0] + hs[(size_t)v * F + lane]) * dv + bias[lane];
        if (RELU) r0 = fmaxf(r0, 0.f);
        out[(size_t)v * F + lane] = r0;
    }
}

extern "C" void kernel_launch(void* const* d_in, const int* in_sizes, int n_in,
                              void* d_out, int out_size, void* d_ws, size_t ws_size,
                              hipStream_t stream)
{
    const float* x  = (const float*)d_in[0];
    const int*   ei = (const int*)d_in[1];
    const float* W1 = (const float*)d_in[2];
    const float* b1 = (const float*)d_in[3];
    const float* W2 = (const float*)d_in[4];
    const float* b2 = (const float*)d_in[5];
    float* out = (float*)d_out;

    const int N = in_sizes[0] / 512;
    const int E = in_sizes[1] / 2;
    const int* src = ei;
    const int* dst = ei + E;

    // workspace layout (16B-aligned regions)
    unsigned* deg      = (unsigned*)d_ws;               // N
    int*      off      = (int*)(deg + N);               // N+1 (pad to N+4)
    unsigned* cursor   = (unsigned*)(off + N + 4);      // N
    unsigned* partials = cursor + N;                    // 1024
    float*    dinv     = (float*)(partials + 1024);     // N
    int*      csr      = (int*)(dinv + N);              // E
    float*    hs       = (float*)(csr + E);             // N*128
    float*    h1       = hs + (size_t)N * 128;          // N*128
    float*    hs2      = hs;                            // N*64 (reuse, hs dead after agg1)

    const int SB = (N + 255) / 256;                     // scan blocks (<=1024)

    hipMemsetAsync(deg, 0, (size_t)N * 4, stream);
    hipMemsetAsync(cursor, 0, (size_t)N * 4, stream);

    // degree + norm
    deg_kernel<<<dim3(2048), 256, 0, stream>>>(dst, E, deg);
    dinv_kernel<<<dim3(SB), 256, 0, stream>>>(deg, dinv, N);

    // CSR build (by dst)
    scan_block<<<dim3(SB), 256, 0, stream>>>(deg, off, partials, N);
    scan_partials<<<dim3(1), 1024, 0, stream>>>(partials, SB);
    add_partials<<<dim3(SB), 256, 0, stream>>>(off, partials, N, E);
    fill_csr<<<dim3(2048), 256, 0, stream>>>(src, dst, E, off, cursor, csr);

    // layer 1
    gemm_scale<128, 512><<<dim3((N + 127) / 128), 256, 0, stream>>>(x, W1, dinv, hs, N);
    agg_pull<128, true><<<dim3((N + 3) / 4), 256, 0, stream>>>(off, csr, hs, dinv, b1, h1, N);

    // layer 2
    gemm_scale<64, 128><<<dim3((N + 127) / 128), 256, 0, stream>>>(h1, W2, dinv, hs2, N);
    agg_pull<64, false><<<dim3((N + 3) / 4), 256, 0, stream>>>(off, csr, hs2, dinv, b2, out, N);
}

// Round 3
// 1099.623 us; speedup vs baseline: 7.9504x; 1.1044x over previous
//
#include <hip/hip_runtime.h>
#include <hip/hip_bf16.h>

// ---------------------------------------------------------------------------
// GCN 2-layer, pull-mode CSR + bf16 messages + split-bf16 MFMA GEMMs.
//   out = Ahat * relu(Ahat * X * W1 + b1) * W2 + b2
//
//  1) deg/dinv, CSR by dst (scan + fill)
//  2) Wt = transpose+split(W) -> bf16 hi/lo [N][K]   (tiny, L2-resident)
//  3) hs  = bf16( (X @ W1) * dinv[row] )   3-term split-bf16 MFMA, zero LDS
//  4) h1  = bf16( relu((sum_in hs + hs[v]) * dinv[v] + b1) )   pull, f32 accum
//  5) hs2 = bf16( (h1 @ W2) * dinv[row] )  2-term (h1 already bf16)
//  6) out = (sum_in hs2 + hs2[v]) * dinv[v] + b2     (f32 out)
// ---------------------------------------------------------------------------

typedef __bf16 bf16x8 __attribute__((ext_vector_type(8)));
typedef float  f32x4  __attribute__((ext_vector_type(4)));

__device__ inline unsigned rne16(float x) {        // f32 -> bf16 bits (RNE)
    unsigned u = __float_as_uint(x);
    return (u + 0x7fffu + ((u >> 16) & 1u)) >> 16;
}

__global__ void deg_kernel(const int* __restrict__ dst, int E, unsigned* __restrict__ deg) {
    int stride = gridDim.x * blockDim.x;
    for (int e = blockIdx.x * blockDim.x + threadIdx.x; e < E; e += stride)
        atomicAdd(&deg[dst[e]], 1u);
}

__global__ void dinv_kernel(const unsigned* __restrict__ deg, float* __restrict__ dinv, int N) {
    int v = blockIdx.x * blockDim.x + threadIdx.x;
    if (v < N) dinv[v] = rsqrtf((float)(deg[v] + 1u));
}

// ---- exclusive scan of deg -> off ----
__global__ void scan_block(const unsigned* __restrict__ deg, int* __restrict__ off,
                           unsigned* __restrict__ partials, int N) {
    __shared__ unsigned s[256];
    int v = blockIdx.x * 256 + threadIdx.x;
    unsigned x = (v < N) ? deg[v] : 0u;
    s[threadIdx.x] = x;
    __syncthreads();
    #pragma unroll
    for (int d = 1; d < 256; d <<= 1) {
        unsigned t = (threadIdx.x >= d) ? s[threadIdx.x - d] : 0u;
        __syncthreads();
        s[threadIdx.x] += t;
        __syncthreads();
    }
    if (v < N) off[v] = (int)(s[threadIdx.x] - x);
    if (threadIdx.x == 255) partials[blockIdx.x] = s[255];
}

__global__ void scan_partials(unsigned* __restrict__ partials, int B) {
    __shared__ unsigned s[1024];
    int i = threadIdx.x;
    unsigned x = (i < B) ? partials[i] : 0u;
    s[i] = x;
    __syncthreads();
    #pragma unroll
    for (int d = 1; d < 1024; d <<= 1) {
        unsigned t = (i >= d) ? s[i - d] : 0u;
        __syncthreads();
        s[i] += t;
        __syncthreads();
    }
    if (i < B) partials[i] = s[i] - x;
}

__global__ void add_partials(int* __restrict__ off, const unsigned* __restrict__ partials,
                             int N, int E) {
    int v = blockIdx.x * 256 + threadIdx.x;
    if (v < N) off[v] += (int)partials[blockIdx.x];
    if (v == 0) off[N] = E;
}

__global__ void fill_csr(const int* __restrict__ src, const int* __restrict__ dst, int E,
                         const int* __restrict__ off, unsigned* __restrict__ cursor,
                         int* __restrict__ csr) {
    int stride = gridDim.x * blockDim.x;
    for (int e = blockIdx.x * blockDim.x + threadIdx.x; e < E; e += stride) {
        int d = dst[e];
        unsigned p = atomicAdd(&cursor[d], 1u);
        csr[off[d] + (int)p] = src[e];
    }
}

// ---- transpose + hi/lo split:  W [K][N] f32  ->  hi/lo [N][K] bf16 ----
__global__ void tsplit(const float* __restrict__ W, __bf16* __restrict__ hi,
                       __bf16* __restrict__ lo, int K, int Nc) {
    int i = blockIdx.x * 256 + threadIdx.x;
    if (i >= K * Nc) return;
    int k = i / Nc, n = i % Nc;
    float f = W[i];
    __bf16 h = (__bf16)f;
    hi[(size_t)n * K + k] = h;
    lo[(size_t)n * K + k] = (__bf16)(f - (float)h);
}

// ---- zero-LDS register MFMA GEMM, C = bf16(A@B * dinv[row]) ----
// A: f32 [M][K] (SPLITA, 3-term) or bf16 [M][K] (2-term). B pre-transposed
// hi/lo bf16 [BN][K] (L2-resident). One wave per 32-row strip, all BN cols.
template <int BN, int K, bool SPLITA>
__global__ __launch_bounds__(256) void gemm_mfma(
    const void* __restrict__ Ap, const __bf16* __restrict__ Bhi,
    const __bf16* __restrict__ Blo, const float* __restrict__ dinv,
    __bf16* __restrict__ C, int M)
{
    constexpr int NC = BN / 16;
    const int lane = threadIdx.x & 63;
    const int wave = threadIdx.x >> 6;
    const int m0 = (blockIdx.x * 4 + wave) * 32;
    if (m0 >= M) return;
    const int lrow = lane & 15;
    const int lk = (lane >> 4) * 8;

    f32x4 acc[2][NC];
    #pragma unroll
    for (int r = 0; r < 2; ++r)
        #pragma unroll
        for (int c = 0; c < NC; ++c) acc[r][c] = (f32x4){0.f, 0.f, 0.f, 0.f};

    for (int kk = 0; kk < K; kk += 32) {
        bf16x8 ah[2], al[2];
        if (SPLITA) {
            const float* A = (const float*)Ap;
            #pragma unroll
            for (int r = 0; r < 2; ++r) {
                const float* p = A + (size_t)(m0 + r * 16 + lrow) * K + kk + lk;
                float4 f0 = *(const float4*)p;
                float4 f1 = *(const float4*)(p + 4);
                float fv[8] = {f0.x, f0.y, f0.z, f0.w, f1.x, f1.y, f1.z, f1.w};
                #pragma unroll
                for (int j = 0; j < 8; ++j) {
                    __bf16 h = (__bf16)fv[j];
                    ah[r][j] = h;
                    al[r][j] = (__bf16)(fv[j] - (float)h);
                }
            }
        } else {
            const __bf16* A = (const __bf16*)Ap;
            #pragma unroll
            for (int r = 0; r < 2; ++r)
                ah[r] = *(const bf16x8*)(A + (size_t)(m0 + r * 16 + lrow) * K + kk + lk);
        }
        #pragma unroll
        for (int c = 0; c < NC; ++c) {
            bf16x8 bh = *(const bf16x8*)(Bhi + (size_t)(c * 16 + lrow) * K + kk + lk);
            bf16x8 bl = *(const bf16x8*)(Blo + (size_t)(c * 16 + lrow) * K + kk + lk);
            #pragma unroll
            for (int r = 0; r < 2; ++r) {
                acc[r][c] = __builtin_amdgcn_mfma_f32_16x16x32_bf16(ah[r], bh, acc[r][c], 0, 0, 0);
                acc[r][c] = __builtin_amdgcn_mfma_f32_16x16x32_bf16(ah[r], bl, acc[r][c], 0, 0, 0);
                if (SPLITA)
                    acc[r][c] = __builtin_amdgcn_mfma_f32_16x16x32_bf16(al[r], bh, acc[r][c], 0, 0, 0);
            }
        }
    }
    // C/D layout: col = lane&15, row = (lane>>4)*4 + j   [guide §3, m89-verified]
    #pragma unroll
    for (int r = 0; r < 2; ++r) {
        #pragma unroll
        for (int j = 0; j < 4; ++j) {
            int m = m0 + r * 16 + (lane >> 4) * 4 + j;
            float dv = dinv[m];
            #pragma unroll
            for (int c = 0; c < NC; ++c)
                C[(size_t)m * BN + c * 16 + (lane & 15)] = (__bf16)(acc[r][c][j] * dv);
        }
    }
}

// ---- pull aggregation F=128 (bf16 in, bf16 out, relu) ----
__global__ __launch_bounds__(256) void agg128(
    const int* __restrict__ off, const int* __restrict__ csr,
    const unsigned* __restrict__ hs,      // bf16x2 rows: 64 dwords per node
    const float* __restrict__ dinv, const float* __restrict__ bias,
    unsigned* __restrict__ h1, int N)
{
    const int lane = threadIdx.x & 63;
    const int v = blockIdx.x * 4 + (threadIdx.x >> 6);
    if (v >= N) return;
    const int s0 = off[v], s1 = off[v + 1];
    float a0 = 0.f, a1 = 0.f;
    for (int e0 = s0; e0 < s1; e0 += 64) {
        int nid = (e0 + lane < s1) ? csr[e0 + lane] : 0;
        int cnt = min(64, s1 - e0);
        for (int j = 0; j < cnt; ++j) {
            int s = __shfl(nid, j);
            unsigned u = hs[(size_t)s * 64 + lane];
            a0 += __uint_as_float(u << 16);
            a1 += __uint_as_float(u & 0xffff0000u);
        }
    }
    unsigned su = hs[(size_t)v * 64 + lane];
    const float dv = dinv[v];
    float r0 = (a0 + __uint_as_float(su << 16)) * dv + bias[lane * 2 + 0];
    float r1 = (a1 + __uint_as_float(su & 0xffff0000u)) * dv + bias[lane * 2 + 1];
    r0 = fmaxf(r0, 0.f);
    r1 = fmaxf(r1, 0.f);
    h1[(size_t)v * 64 + lane] = rne16(r0) | (rne16(r1) << 16);
}

// ---- pull aggregation F=64 (bf16 in, f32 out) ----
__global__ __launch_bounds__(256) void agg64(
    const int* __restrict__ off, const int* __restrict__ csr,
    const unsigned short* __restrict__ hs2, const float* __restrict__ dinv,
    const float* __restrict__ bias, float* __restrict__ out, int N)
{
    const int lane = threadIdx.x & 63;
    const int v = blockIdx.x * 4 + (threadIdx.x >> 6);
    if (v >= N) return;
    const int s0 = off[v], s1 = off[v + 1];
    float a0 = 0.f;
    for (int e0 = s0; e0 < s1; e0 += 64) {
        int nid = (e0 + lane < s1) ? csr[e0 + lane] : 0;
        int cnt = min(64, s1 - e0);
        for (int j = 0; j < cnt; ++j) {
            int s = __shfl(nid, j);
            a0 += __uint_as_float((unsigned)hs2[(size_t)s * 64 + lane] << 16);
        }
    }
    float self = __uint_as_float((unsigned)hs2[(size_t)v * 64 + lane] << 16);
    out[(size_t)v * 64 + lane] = (a0 + self) * dinv[v] + bias[lane];
}

extern "C" void kernel_launch(void* const* d_in, const int* in_sizes, int n_in,
                              void* d_out, int out_size, void* d_ws, size_t ws_size,
                              hipStream_t stream)
{
    const float* x  = (const float*)d_in[0];
    const int*   ei = (const int*)d_in[1];
    const float* W1 = (const float*)d_in[2];
    const float* b1 = (const float*)d_in[3];
    const float* W2 = (const float*)d_in[4];
    const float* b2 = (const float*)d_in[5];
    float* out = (float*)d_out;

    const int N = in_sizes[0] / 512;
    const int E = in_sizes[1] / 2;
    const int* src = ei;
    const int* dst = ei + E;

    // ---- workspace layout ----
    unsigned* deg      = (unsigned*)d_ws;               // N
    unsigned* cursor   = deg + N;                       // N   (adjacent: one memset)
    int*      off      = (int*)(cursor + N);            // N+4
    unsigned* partials = (unsigned*)(off + N + 4);      // 1024
    float*    dinv     = (float*)(partials + 1024);     // N
    int*      csr      = (int*)(dinv + N);              // E
    __bf16*   Bt1hi    = (__bf16*)(csr + E);            // 128*512
    __bf16*   Bt1lo    = Bt1hi + 128 * 512;
    __bf16*   Bt2hi    = Bt1lo + 128 * 512;             // 64*128
    __bf16*   Bt2lo    = Bt2hi + 64 * 128;
    __bf16*   hs       = Bt2lo + 64 * 128;              // N*128 bf16
    __bf16*   h1       = hs + (size_t)N * 128;          // N*128 bf16
    __bf16*   hs2      = h1 + (size_t)N * 128;          // N*64  bf16

    const int SB = (N + 255) / 256;

    hipMemsetAsync(deg, 0, (size_t)N * 8, stream);      // deg + cursor

    deg_kernel<<<dim3(2048), 256, 0, stream>>>(dst, E, deg);
    dinv_kernel<<<dim3(SB), 256, 0, stream>>>(deg, dinv, N);

    scan_block<<<dim3(SB), 256, 0, stream>>>(deg, off, partials, N);
    scan_partials<<<dim3(1), 1024, 0, stream>>>(partials, SB);
    add_partials<<<dim3(SB), 256, 0, stream>>>(off, partials, N, E);
    fill_csr<<<dim3(2048), 256, 0, stream>>>(src, dst, E, off, cursor, csr);

    tsplit<<<dim3((512 * 128 + 255) / 256), 256, 0, stream>>>(W1, Bt1hi, Bt1lo, 512, 128);
    tsplit<<<dim3((128 * 64 + 255) / 256), 256, 0, stream>>>(W2, Bt2hi, Bt2lo, 128, 64);

    // layer 1
    gemm_mfma<128, 512, true><<<dim3((N + 127) / 128), 256, 0, stream>>>(
        x, Bt1hi, Bt1lo, dinv, hs, N);
    agg128<<<dim3((N + 3) / 4), 256, 0, stream>>>(
        off, csr, (const unsigned*)hs, dinv, b1, (unsigned*)h1, N);

    // layer 2
    gemm_mfma<64, 128, false><<<dim3((N + 127) / 128), 256, 0, stream>>>(
        h1, Bt2hi, Bt2lo, dinv, hs2, N);
    agg64<<<dim3((N + 3) / 4), 256, 0, stream>>>(
        off, csr, (const unsigned short*)hs2, dinv, b2, out, N);
}

// Round 4
// 972.606 us; speedup vs baseline: 8.9887x; 1.1306x over previous
//
#include <hip/hip_runtime.h>
#include <hip/hip_bf16.h>

// ---------------------------------------------------------------------------
// GCN 2-layer, pull-mode CSR + bf16 messages + split-bf16 MFMA GEMMs.
//   out = Ahat * relu(Ahat * X * W1 + b1) * W2 + b2
// R4: agg neighbor loop unrolled x8 (MLP), dinv fused into scan_block.
// ---------------------------------------------------------------------------

typedef __bf16 bf16x8 __attribute__((ext_vector_type(8)));
typedef float  f32x4  __attribute__((ext_vector_type(4)));

__device__ inline unsigned rne16(float x) {        // f32 -> bf16 bits (RNE)
    unsigned u = __float_as_uint(x);
    return (u + 0x7fffu + ((u >> 16) & 1u)) >> 16;
}

__global__ void deg_kernel(const int* __restrict__ dst, int E, unsigned* __restrict__ deg) {
    int stride = gridDim.x * blockDim.x;
    for (int e = blockIdx.x * blockDim.x + threadIdx.x; e < E; e += stride)
        atomicAdd(&deg[dst[e]], 1u);
}

// ---- exclusive scan of deg -> off, plus dinv = rsqrt(deg+1) fused ----
__global__ void scan_block(const unsigned* __restrict__ deg, int* __restrict__ off,
                           unsigned* __restrict__ partials, float* __restrict__ dinv, int N) {
    __shared__ unsigned s[256];
    int v = blockIdx.x * 256 + threadIdx.x;
    unsigned x = (v < N) ? deg[v] : 0u;
    s[threadIdx.x] = x;
    __syncthreads();
    #pragma unroll
    for (int d = 1; d < 256; d <<= 1) {
        unsigned t = (threadIdx.x >= d) ? s[threadIdx.x - d] : 0u;
        __syncthreads();
        s[threadIdx.x] += t;
        __syncthreads();
    }
    if (v < N) {
        off[v] = (int)(s[threadIdx.x] - x);
        dinv[v] = rsqrtf((float)(x + 1u));
    }
    if (threadIdx.x == 255) partials[blockIdx.x] = s[255];
}

__global__ void scan_partials(unsigned* __restrict__ partials, int B) {
    __shared__ unsigned s[1024];
    int i = threadIdx.x;
    unsigned x = (i < B) ? partials[i] : 0u;
    s[i] = x;
    __syncthreads();
    #pragma unroll
    for (int d = 1; d < 1024; d <<= 1) {
        unsigned t = (i >= d) ? s[i - d] : 0u;
        __syncthreads();
        s[i] += t;
        __syncthreads();
    }
    if (i < B) partials[i] = s[i] - x;
}

__global__ void add_partials(int* __restrict__ off, const unsigned* __restrict__ partials,
                             int N, int E) {
    int v = blockIdx.x * 256 + threadIdx.x;
    if (v < N) off[v] += (int)partials[blockIdx.x];
    if (v == 0) off[N] = E;
}

__global__ void fill_csr(const int* __restrict__ src, const int* __restrict__ dst, int E,
                         const int* __restrict__ off, unsigned* __restrict__ cursor,
                         int* __restrict__ csr) {
    int stride = gridDim.x * blockDim.x;
    for (int e = blockIdx.x * blockDim.x + threadIdx.x; e < E; e += stride) {
        int d = dst[e];
        unsigned p = atomicAdd(&cursor[d], 1u);
        csr[off[d] + (int)p] = src[e];
    }
}

// ---- transpose + hi/lo split:  W [K][N] f32  ->  hi/lo [N][K] bf16 ----
__global__ void tsplit(const float* __restrict__ W, __bf16* __restrict__ hi,
                       __bf16* __restrict__ lo, int K, int Nc) {
    int i = blockIdx.x * 256 + threadIdx.x;
    if (i >= K * Nc) return;
    int k = i / Nc, n = i % Nc;
    float f = W[i];
    __bf16 h = (__bf16)f;
    hi[(size_t)n * K + k] = h;
    lo[(size_t)n * K + k] = (__bf16)(f - (float)h);
}

// ---- zero-LDS register MFMA GEMM, C = bf16(A@B * dinv[row]) ----
template <int BN, int K, bool SPLITA>
__global__ __launch_bounds__(256) void gemm_mfma(
    const void* __restrict__ Ap, const __bf16* __restrict__ Bhi,
    const __bf16* __restrict__ Blo, const float* __restrict__ dinv,
    __bf16* __restrict__ C, int M)
{
    constexpr int NC = BN / 16;
    const int lane = threadIdx.x & 63;
    const int wave = threadIdx.x >> 6;
    const int m0 = (blockIdx.x * 4 + wave) * 32;
    if (m0 >= M) return;
    const int lrow = lane & 15;
    const int lk = (lane >> 4) * 8;

    f32x4 acc[2][NC];
    #pragma unroll
    for (int r = 0; r < 2; ++r)
        #pragma unroll
        for (int c = 0; c < NC; ++c) acc[r][c] = (f32x4){0.f, 0.f, 0.f, 0.f};

    for (int kk = 0; kk < K; kk += 32) {
        bf16x8 ah[2], al[2];
        if (SPLITA) {
            const float* A = (const float*)Ap;
            #pragma unroll
            for (int r = 0; r < 2; ++r) {
                const float* p = A + (size_t)(m0 + r * 16 + lrow) * K + kk + lk;
                float4 f0 = *(const float4*)p;
                float4 f1 = *(const float4*)(p + 4);
                float fv[8] = {f0.x, f0.y, f0.z, f0.w, f1.x, f1.y, f1.z, f1.w};
                #pragma unroll
                for (int j = 0; j < 8; ++j) {
                    __bf16 h = (__bf16)fv[j];
                    ah[r][j] = h;
                    al[r][j] = (__bf16)(fv[j] - (float)h);
                }
            }
        } else {
            const __bf16* A = (const __bf16*)Ap;
            #pragma unroll
            for (int r = 0; r < 2; ++r)
                ah[r] = *(const bf16x8*)(A + (size_t)(m0 + r * 16 + lrow) * K + kk + lk);
        }
        #pragma unroll
        for (int c = 0; c < NC; ++c) {
            bf16x8 bh = *(const bf16x8*)(Bhi + (size_t)(c * 16 + lrow) * K + kk + lk);
            bf16x8 bl = *(const bf16x8*)(Blo + (size_t)(c * 16 + lrow) * K + kk + lk);
            #pragma unroll
            for (int r = 0; r < 2; ++r) {
                acc[r][c] = __builtin_amdgcn_mfma_f32_16x16x32_bf16(ah[r], bh, acc[r][c], 0, 0, 0);
                acc[r][c] = __builtin_amdgcn_mfma_f32_16x16x32_bf16(ah[r], bl, acc[r][c], 0, 0, 0);
                if (SPLITA)
                    acc[r][c] = __builtin_amdgcn_mfma_f32_16x16x32_bf16(al[r], bh, acc[r][c], 0, 0, 0);
            }
        }
    }
    #pragma unroll
    for (int r = 0; r < 2; ++r) {
        #pragma unroll
        for (int j = 0; j < 4; ++j) {
            int m = m0 + r * 16 + (lane >> 4) * 4 + j;
            float dv = dinv[m];
            #pragma unroll
            for (int c = 0; c < NC; ++c)
                C[(size_t)m * BN + c * 16 + (lane & 15)] = (__bf16)(acc[r][c][j] * dv);
        }
    }
}

// ---- pull aggregation F=128 (bf16 in, bf16 out, relu), unroll x8 ----
__global__ __launch_bounds__(256) void agg128(
    const int* __restrict__ off, const int* __restrict__ csr,
    const unsigned* __restrict__ hs,      // bf16x2 rows: 64 dwords per node
    const float* __restrict__ dinv, const float* __restrict__ bias,
    unsigned* __restrict__ h1, int N)
{
    const int lane = threadIdx.x & 63;
    const int v = blockIdx.x * 4 + (threadIdx.x >> 6);
    if (v >= N) return;
    const int s0 = off[v], s1 = off[v + 1];
    float a0 = 0.f, a1 = 0.f;
    for (int e0 = s0; e0 < s1; e0 += 64) {
        int nid = (e0 + lane < s1) ? csr[e0 + lane] : 0;
        int cnt = min(64, s1 - e0);
        int j = 0;
        for (; j + 8 <= cnt; j += 8) {
            unsigned u[8];
            #pragma unroll
            for (int q = 0; q < 8; ++q) {
                int s = __shfl(nid, j + q);
                u[q] = hs[(size_t)s * 64 + lane];
            }
            #pragma unroll
            for (int q = 0; q < 8; ++q) {
                a0 += __uint_as_float(u[q] << 16);
                a1 += __uint_as_float(u[q] & 0xffff0000u);
            }
        }
        for (; j < cnt; ++j) {
            int s = __shfl(nid, j);
            unsigned u = hs[(size_t)s * 64 + lane];
            a0 += __uint_as_float(u << 16);
            a1 += __uint_as_float(u & 0xffff0000u);
        }
    }
    unsigned su = hs[(size_t)v * 64 + lane];
    const float dv = dinv[v];
    float r0 = (a0 + __uint_as_float(su << 16)) * dv + bias[lane * 2 + 0];
    float r1 = (a1 + __uint_as_float(su & 0xffff0000u)) * dv + bias[lane * 2 + 1];
    r0 = fmaxf(r0, 0.f);
    r1 = fmaxf(r1, 0.f);
    h1[(size_t)v * 64 + lane] = rne16(r0) | (rne16(r1) << 16);
}

// ---- pull aggregation F=64 (bf16 in, f32 out), unroll x8 ----
__global__ __launch_bounds__(256) void agg64(
    const int* __restrict__ off, const int* __restrict__ csr,
    const unsigned short* __restrict__ hs2, const float* __restrict__ dinv,
    const float* __restrict__ bias, float* __restrict__ out, int N)
{
    const int lane = threadIdx.x & 63;
    const int v = blockIdx.x * 4 + (threadIdx.x >> 6);
    if (v >= N) return;
    const int s0 = off[v], s1 = off[v + 1];
    float a0 = 0.f;
    for (int e0 = s0; e0 < s1; e0 += 64) {
        int nid = (e0 + lane < s1) ? csr[e0 + lane] : 0;
        int cnt = min(64, s1 - e0);
        int j = 0;
        for (; j + 8 <= cnt; j += 8) {
            unsigned short u[8];
            #pragma unroll
            for (int q = 0; q < 8; ++q) {
                int s = __shfl(nid, j + q);
                u[q] = hs2[(size_t)s * 64 + lane];
            }
            #pragma unroll
            for (int q = 0; q < 8; ++q)
                a0 += __uint_as_float((unsigned)u[q] << 16);
        }
        for (; j < cnt; ++j) {
            int s = __shfl(nid, j);
            a0 += __uint_as_float((unsigned)hs2[(size_t)s * 64 + lane] << 16);
        }
    }
    float self = __uint_as_float((unsigned)hs2[(size_t)v * 64 + lane] << 16);
    out[(size_t)v * 64 + lane] = (a0 + self) * dinv[v] + bias[lane];
}

extern "C" void kernel_launch(void* const* d_in, const int* in_sizes, int n_in,
                              void* d_out, int out_size, void* d_ws, size_t ws_size,
                              hipStream_t stream)
{
    const float* x  = (const float*)d_in[0];
    const int*   ei = (const int*)d_in[1];
    const float* W1 = (const float*)d_in[2];
    const float* b1 = (const float*)d_in[3];
    const float* W2 = (const float*)d_in[4];
    const float* b2 = (const float*)d_in[5];
    float* out = (float*)d_out;

    const int N = in_sizes[0] / 512;
    const int E = in_sizes[1] / 2;
    const int* src = ei;
    const int* dst = ei + E;

    // ---- workspace layout ----
    unsigned* deg      = (unsigned*)d_ws;               // N
    unsigned* cursor   = deg + N;                       // N   (adjacent: one memset)
    int*      off      = (int*)(cursor + N);            // N+4
    unsigned* partials = (unsigned*)(off + N + 4);      // 1024
    float*    dinv     = (float*)(partials + 1024);     // N
    int*      csr      = (int*)(dinv + N);              // E
    __bf16*   Bt1hi    = (__bf16*)(csr + E);            // 128*512
    __bf16*   Bt1lo    = Bt1hi + 128 * 512;
    __bf16*   Bt2hi    = Bt1lo + 128 * 512;             // 64*128
    __bf16*   Bt2lo    = Bt2hi + 64 * 128;
    __bf16*   hs       = Bt2lo + 64 * 128;              // N*128 bf16
    __bf16*   h1       = hs + (size_t)N * 128;          // N*128 bf16
    __bf16*   hs2      = h1 + (size_t)N * 128;          // N*64  bf16

    const int SB = (N + 255) / 256;

    hipMemsetAsync(deg, 0, (size_t)N * 8, stream);      // deg + cursor

    deg_kernel<<<dim3(2048), 256, 0, stream>>>(dst, E, deg);

    scan_block<<<dim3(SB), 256, 0, stream>>>(deg, off, partials, dinv, N);
    scan_partials<<<dim3(1), 1024, 0, stream>>>(partials, SB);
    add_partials<<<dim3(SB), 256, 0, stream>>>(off, partials, N, E);
    fill_csr<<<dim3(2048), 256, 0, stream>>>(src, dst, E, off, cursor, csr);

    tsplit<<<dim3((512 * 128 + 255) / 256), 256, 0, stream>>>(W1, Bt1hi, Bt1lo, 512, 128);
    tsplit<<<dim3((128 * 64 + 255) / 256), 256, 0, stream>>>(W2, Bt2hi, Bt2lo, 128, 64);

    // layer 1
    gemm_mfma<128, 512, true><<<dim3((N + 127) / 128), 256, 0, stream>>>(
        x, Bt1hi, Bt1lo, dinv, hs, N);
    agg128<<<dim3((N + 3) / 4), 256, 0, stream>>>(
        off, csr, (const unsigned*)hs, dinv, b1, (unsigned*)h1, N);

    // layer 2
    gemm_mfma<64, 128, false><<<dim3((N + 127) / 128), 256, 0, stream>>>(
        h1, Bt2hi, Bt2lo, dinv, hs2, N);
    agg64<<<dim3((N + 3) / 4), 256, 0, stream>>>(
        off, csr, (const unsigned short*)hs2, dinv, b2, out, N);
}

// Round 5
// 967.059 us; speedup vs baseline: 9.0402x; 1.0057x over previous
//
#include <hip/hip_runtime.h>
#include <hip/hip_bf16.h>

// ---------------------------------------------------------------------------
// GCN 2-layer, pull-mode CSR + bf16 messages + split-bf16 MFMA GEMMs.
//   out = Ahat * relu(Ahat * X * W1 + b1) * W2 + b2
// R5: col-split waves (4x wave parallelism), LDS-staged A split in gemm1.
// ---------------------------------------------------------------------------

typedef __bf16 bf16x8 __attribute__((ext_vector_type(8)));
typedef __bf16 bf16x4 __attribute__((ext_vector_type(4)));
typedef float  f32x4  __attribute__((ext_vector_type(4)));

__device__ inline unsigned rne16(float x) {        // f32 -> bf16 bits (RNE)
    unsigned u = __float_as_uint(x);
    return (u + 0x7fffu + ((u >> 16) & 1u)) >> 16;
}

__global__ void deg_kernel(const int* __restrict__ dst, int E, unsigned* __restrict__ deg) {
    int stride = gridDim.x * blockDim.x;
    for (int e = blockIdx.x * blockDim.x + threadIdx.x; e < E; e += stride)
        atomicAdd(&deg[dst[e]], 1u);
}

// ---- exclusive scan of deg -> off, plus dinv = rsqrt(deg+1) fused ----
__global__ void scan_block(const unsigned* __restrict__ deg, int* __restrict__ off,
                           unsigned* __restrict__ partials, float* __restrict__ dinv, int N) {
    __shared__ unsigned s[256];
    int v = blockIdx.x * 256 + threadIdx.x;
    unsigned x = (v < N) ? deg[v] : 0u;
    s[threadIdx.x] = x;
    __syncthreads();
    #pragma unroll
    for (int d = 1; d < 256; d <<= 1) {
        unsigned t = (threadIdx.x >= d) ? s[threadIdx.x - d] : 0u;
        __syncthreads();
        s[threadIdx.x] += t;
        __syncthreads();
    }
    if (v < N) {
        off[v] = (int)(s[threadIdx.x] - x);
        dinv[v] = rsqrtf((float)(x + 1u));
    }
    if (threadIdx.x == 255) partials[blockIdx.x] = s[255];
}

__global__ void scan_partials(unsigned* __restrict__ partials, int B) {
    __shared__ unsigned s[1024];
    int i = threadIdx.x;
    unsigned x = (i < B) ? partials[i] : 0u;
    s[i] = x;
    __syncthreads();
    #pragma unroll
    for (int d = 1; d < 1024; d <<= 1) {
        unsigned t = (i >= d) ? s[i - d] : 0u;
        __syncthreads();
        s[i] += t;
        __syncthreads();
    }
    if (i < B) partials[i] = s[i] - x;
}

__global__ void add_partials(int* __restrict__ off, const unsigned* __restrict__ partials,
                             int N, int E) {
    int v = blockIdx.x * 256 + threadIdx.x;
    if (v < N) off[v] += (int)partials[blockIdx.x];
    if (v == 0) off[N] = E;
}

__global__ void fill_csr(const int* __restrict__ src, const int* __restrict__ dst, int E,
                         const int* __restrict__ off, unsigned* __restrict__ cursor,
                         int* __restrict__ csr) {
    int stride = gridDim.x * blockDim.x;
    for (int e = blockIdx.x * blockDim.x + threadIdx.x; e < E; e += stride) {
        int d = dst[e];
        unsigned p = atomicAdd(&cursor[d], 1u);
        csr[off[d] + (int)p] = src[e];
    }
}

// ---- transpose + hi/lo split:  W [K][N] f32  ->  hi/lo [N][K] bf16 ----
__global__ void tsplit(const float* __restrict__ W, __bf16* __restrict__ hi,
                       __bf16* __restrict__ lo, int K, int Nc) {
    int i = blockIdx.x * 256 + threadIdx.x;
    if (i >= K * Nc) return;
    int k = i / Nc, n = i % Nc;
    float f = W[i];
    __bf16 h = (__bf16)f;
    hi[(size_t)n * K + k] = h;
    lo[(size_t)n * K + k] = (__bf16)(f - (float)h);
}

// ---- layer-1 GEMM: C = bf16((X @ W1) * dinv[row]), 3-term split-bf16 ----
// Block: 32 rows; A tile split f32->hi/lo bf16 in LDS once per block.
// 4 waves col-split: wave w computes 32 rows x cols [w*32, w*32+32), K=512.
template <int K>
__global__ __launch_bounds__(256) void gemm1_mfma(
    const float* __restrict__ A, const __bf16* __restrict__ Bhi,
    const __bf16* __restrict__ Blo, const float* __restrict__ dinv,
    __bf16* __restrict__ C, int M)
{
    constexpr int LDA = 40;                        // padded row (bf16) -> 2-way max
    __shared__ __bf16 shi[32][LDA];
    __shared__ __bf16 slo[32][LDA];

    const int tid = threadIdx.x;
    const int lane = tid & 63;
    const int wave = tid >> 6;
    const int m0 = blockIdx.x * 32;
    const int col0 = wave * 32;
    const int lrow = lane & 15;
    const int lk = (lane >> 4) * 8;
    const int arow = tid >> 3;                     // loader: 8 threads/row
    const int ac4 = (tid & 7) * 4;

    f32x4 acc[2][2];
    #pragma unroll
    for (int r = 0; r < 2; ++r)
        #pragma unroll
        for (int c = 0; c < 2; ++c) acc[r][c] = (f32x4){0.f, 0.f, 0.f, 0.f};

    #pragma unroll 1
    for (int kk = 0; kk < K; kk += 32) {
        __syncthreads();                           // prev compute done
        {
            int gr = m0 + arow; if (gr >= M) gr = M - 1;
            float4 f = *(const float4*)(A + (size_t)gr * K + kk + ac4);
            bf16x4 h, l;
            h[0] = (__bf16)f.x; l[0] = (__bf16)(f.x - (float)h[0]);
            h[1] = (__bf16)f.y; l[1] = (__bf16)(f.y - (float)h[1]);
            h[2] = (__bf16)f.z; l[2] = (__bf16)(f.z - (float)h[2]);
            h[3] = (__bf16)f.w; l[3] = (__bf16)(f.w - (float)h[3]);
            *(bf16x4*)&shi[arow][ac4] = h;
            *(bf16x4*)&slo[arow][ac4] = l;
        }
        __syncthreads();
        bf16x8 ah[2], al[2];
        #pragma unroll
        for (int r = 0; r < 2; ++r) {
            ah[r] = *(const bf16x8*)&shi[r * 16 + lrow][lk];
            al[r] = *(const bf16x8*)&slo[r * 16 + lrow][lk];
        }
        #pragma unroll
        for (int c = 0; c < 2; ++c) {
            bf16x8 bh = *(const bf16x8*)(Bhi + (size_t)(col0 + c * 16 + lrow) * K + kk + lk);
            bf16x8 bl = *(const bf16x8*)(Blo + (size_t)(col0 + c * 16 + lrow) * K + kk + lk);
            #pragma unroll
            for (int r = 0; r < 2; ++r) {
                acc[r][c] = __builtin_amdgcn_mfma_f32_16x16x32_bf16(ah[r], bh, acc[r][c], 0, 0, 0);
                acc[r][c] = __builtin_amdgcn_mfma_f32_16x16x32_bf16(ah[r], bl, acc[r][c], 0, 0, 0);
                acc[r][c] = __builtin_amdgcn_mfma_f32_16x16x32_bf16(al[r], bh, acc[r][c], 0, 0, 0);
            }
        }
    }
    // C/D layout: col = lane&15, row = (lane>>4)*4 + j
    #pragma unroll
    for (int r = 0; r < 2; ++r) {
        #pragma unroll
        for (int j = 0; j < 4; ++j) {
            int m = m0 + r * 16 + (lane >> 4) * 4 + j;
            if (m >= M) continue;
            float dv = dinv[m];
            #pragma unroll
            for (int c = 0; c < 2; ++c)
                C[(size_t)m * 128 + col0 + c * 16 + lrow] = (__bf16)(acc[r][c][j] * dv);
        }
    }
}

// ---- layer-2 GEMM: C = bf16((h1 @ W2) * dinv[row]), A already bf16 ----
// Block: 64 rows, 4 waves: rg = wave>>1 (32-row group), cg = wave&1 (32 cols).
template <int K>
__global__ __launch_bounds__(256) void gemm2_mfma(
    const __bf16* __restrict__ A, const __bf16* __restrict__ Bhi,
    const __bf16* __restrict__ Blo, const float* __restrict__ dinv,
    __bf16* __restrict__ C, int M)
{
    const int lane = threadIdx.x & 63;
    const int wave = threadIdx.x >> 6;
    const int m0 = blockIdx.x * 64 + (wave >> 1) * 32;
    const int col0 = (wave & 1) * 32;
    const int lrow = lane & 15;
    const int lk = (lane >> 4) * 8;

    f32x4 acc[2][2];
    #pragma unroll
    for (int r = 0; r < 2; ++r)
        #pragma unroll
        for (int c = 0; c < 2; ++c) acc[r][c] = (f32x4){0.f, 0.f, 0.f, 0.f};

    #pragma unroll
    for (int kk = 0; kk < K; kk += 32) {
        bf16x8 ah[2];
        #pragma unroll
        for (int r = 0; r < 2; ++r) {
            int gr = m0 + r * 16 + lrow; if (gr >= M) gr = M - 1;
            ah[r] = *(const bf16x8*)(A + (size_t)gr * K + kk + lk);
        }
        #pragma unroll
        for (int c = 0; c < 2; ++c) {
            bf16x8 bh = *(const bf16x8*)(Bhi + (size_t)(col0 + c * 16 + lrow) * K + kk + lk);
            bf16x8 bl = *(const bf16x8*)(Blo + (size_t)(col0 + c * 16 + lrow) * K + kk + lk);
            #pragma unroll
            for (int r = 0; r < 2; ++r) {
                acc[r][c] = __builtin_amdgcn_mfma_f32_16x16x32_bf16(ah[r], bh, acc[r][c], 0, 0, 0);
                acc[r][c] = __builtin_amdgcn_mfma_f32_16x16x32_bf16(ah[r], bl, acc[r][c], 0, 0, 0);
            }
        }
    }
    #pragma unroll
    for (int r = 0; r < 2; ++r) {
        #pragma unroll
        for (int j = 0; j < 4; ++j) {
            int m = m0 + r * 16 + (lane >> 4) * 4 + j;
            if (m >= M) continue;
            float dv = dinv[m];
            #pragma unroll
            for (int c = 0; c < 2; ++c)
                C[(size_t)m * 64 + col0 + c * 16 + lrow] = (__bf16)(acc[r][c][j] * dv);
        }
    }
}

// ---- pull aggregation F=128 (bf16 in, bf16 out, relu), unroll x8 ----
__global__ __launch_bounds__(256) void agg128(
    const int* __restrict__ off, const int* __restrict__ csr,
    const unsigned* __restrict__ hs,      // bf16x2 rows: 64 dwords per node
    const float* __restrict__ dinv, const float* __restrict__ bias,
    unsigned* __restrict__ h1, int N)
{
    const int lane = threadIdx.x & 63;
    const int v = blockIdx.x * 4 + (threadIdx.x >> 6);
    if (v >= N) return;
    const int s0 = off[v], s1 = off[v + 1];
    float a0 = 0.f, a1 = 0.f;
    for (int e0 = s0; e0 < s1; e0 += 64) {
        int nid = (e0 + lane < s1) ? csr[e0 + lane] : 0;
        int cnt = min(64, s1 - e0);
        int j = 0;
        for (; j + 8 <= cnt; j += 8) {
            unsigned u[8];
            #pragma unroll
            for (int q = 0; q < 8; ++q) {
                int s = __shfl(nid, j + q);
                u[q] = hs[(size_t)s * 64 + lane];
            }
            #pragma unroll
            for (int q = 0; q < 8; ++q) {
                a0 += __uint_as_float(u[q] << 16);
                a1 += __uint_as_float(u[q] & 0xffff0000u);
            }
        }
        for (; j < cnt; ++j) {
            int s = __shfl(nid, j);
            unsigned u = hs[(size_t)s * 64 + lane];
            a0 += __uint_as_float(u << 16);
            a1 += __uint_as_float(u & 0xffff0000u);
        }
    }
    unsigned su = hs[(size_t)v * 64 + lane];
    const float dv = dinv[v];
    float r0 = (a0 + __uint_as_float(su << 16)) * dv + bias[lane * 2 + 0];
    float r1 = (a1 + __uint_as_float(su & 0xffff0000u)) * dv + bias[lane * 2 + 1];
    r0 = fmaxf(r0, 0.f);
    r1 = fmaxf(r1, 0.f);
    h1[(size_t)v * 64 + lane] = rne16(r0) | (rne16(r1) << 16);
}

// ---- pull aggregation F=64 (bf16 in, f32 out), unroll x8 ----
__global__ __launch_bounds__(256) void agg64(
    const int* __restrict__ off, const int* __restrict__ csr,
    const unsigned short* __restrict__ hs2, const float* __restrict__ dinv,
    const float* __restrict__ bias, float* __restrict__ out, int N)
{
    const int lane = threadIdx.x & 63;
    const int v = blockIdx.x * 4 + (threadIdx.x >> 6);
    if (v >= N) return;
    const int s0 = off[v], s1 = off[v + 1];
    float a0 = 0.f;
    for (int e0 = s0; e0 < s1; e0 += 64) {
        int nid = (e0 + lane < s1) ? csr[e0 + lane] : 0;
        int cnt = min(64, s1 - e0);
        int j = 0;
        for (; j + 8 <= cnt; j += 8) {
            unsigned short u[8];
            #pragma unroll
            for (int q = 0; q < 8; ++q) {
                int s = __shfl(nid, j + q);
                u[q] = hs2[(size_t)s * 64 + lane];
            }
            #pragma unroll
            for (int q = 0; q < 8; ++q)
                a0 += __uint_as_float((unsigned)u[q] << 16);
        }
        for (; j < cnt; ++j) {
            int s = __shfl(nid, j);
            a0 += __uint_as_float((unsigned)hs2[(size_t)s * 64 + lane] << 16);
        }
    }
    float self = __uint_as_float((unsigned)hs2[(size_t)v * 64 + lane] << 16);
    out[(size_t)v * 64 + lane] = (a0 + self) * dinv[v] + bias[lane];
}

extern "C" void kernel_launch(void* const* d_in, const int* in_sizes, int n_in,
                              void* d_out, int out_size, void* d_ws, size_t ws_size,
                              hipStream_t stream)
{
    const float* x  = (const float*)d_in[0];
    const int*   ei = (const int*)d_in[1];
    const float* W1 = (const float*)d_in[2];
    const float* b1 = (const float*)d_in[3];
    const float* W2 = (const float*)d_in[4];
    const float* b2 = (const float*)d_in[5];
    float* out = (float*)d_out;

    const int N = in_sizes[0] / 512;
    const int E = in_sizes[1] / 2;
    const int* src = ei;
    const int* dst = ei + E;

    // ---- workspace layout ----
    unsigned* deg      = (unsigned*)d_ws;               // N
    unsigned* cursor   = deg + N;                       // N   (adjacent: one memset)
    int*      off      = (int*)(cursor + N);            // N+4
    unsigned* partials = (unsigned*)(off + N + 4);      // 1024
    float*    dinv     = (float*)(partials + 1024);     // N
    int*      csr      = (int*)(dinv + N);              // E
    __bf16*   Bt1hi    = (__bf16*)(csr + E);            // 128*512
    __bf16*   Bt1lo    = Bt1hi + 128 * 512;
    __bf16*   Bt2hi    = Bt1lo + 128 * 512;             // 64*128
    __bf16*   Bt2lo    = Bt2hi + 64 * 128;
    __bf16*   hs       = Bt2lo + 64 * 128;              // N*128 bf16
    __bf16*   h1       = hs + (size_t)N * 128;          // N*128 bf16
    __bf16*   hs2      = h1 + (size_t)N * 128;          // N*64  bf16

    const int SB = (N + 255) / 256;

    hipMemsetAsync(deg, 0, (size_t)N * 8, stream);      // deg + cursor

    deg_kernel<<<dim3(2048), 256, 0, stream>>>(dst, E, deg);

    scan_block<<<dim3(SB), 256, 0, stream>>>(deg, off, partials, dinv, N);
    scan_partials<<<dim3(1), 1024, 0, stream>>>(partials, SB);
    add_partials<<<dim3(SB), 256, 0, stream>>>(off, partials, N, E);
    fill_csr<<<dim3(2048), 256, 0, stream>>>(src, dst, E, off, cursor, csr);

    tsplit<<<dim3((512 * 128 + 255) / 256), 256, 0, stream>>>(W1, Bt1hi, Bt1lo, 512, 128);
    tsplit<<<dim3((128 * 64 + 255) / 256), 256, 0, stream>>>(W2, Bt2hi, Bt2lo, 128, 64);

    // layer 1
    gemm1_mfma<512><<<dim3((N + 31) / 32), 256, 0, stream>>>(x, Bt1hi, Bt1lo, dinv, hs, N);
    agg128<<<dim3((N + 3) / 4), 256, 0, stream>>>(
        off, csr, (const unsigned*)hs, dinv, b1, (unsigned*)h1, N);

    // layer 2
    gemm2_mfma<128><<<dim3((N + 63) / 64), 256, 0, stream>>>(h1, Bt2hi, Bt2lo, dinv, hs2, N);
    agg64<<<dim3((N + 3) / 4), 256, 0, stream>>>(
        off, csr, (const unsigned short*)hs2, dinv, b2, out, N);
}

// Round 6
// 809.650 us; speedup vs baseline: 10.7978x; 1.1944x over previous
//
#include <hip/hip_runtime.h>
#include <hip/hip_bf16.h>

// ---------------------------------------------------------------------------
// GCN 2-layer, pull-mode CSR + bf16 messages + split-bf16 MFMA GEMMs.
//   out = Ahat * relu(Ahat * X * W1 + b1) * W2 + b2
// R6: bucket-sort CSR build (no 3.2M-atomic kernels), dbuf gemm1 (1 barrier/kk).
// ---------------------------------------------------------------------------

typedef __bf16 bf16x8 __attribute__((ext_vector_type(8)));
typedef __bf16 bf16x4 __attribute__((ext_vector_type(4)));
typedef float  f32x4  __attribute__((ext_vector_type(4)));

#define NBSHIFT 7          // 128 nodes per bucket
#define CSR_CAP 8192       // max edges per bucket staged in LDS (mean 4096, sd 64)

__device__ inline unsigned rne16(float x) {        // f32 -> bf16 bits (RNE)
    unsigned u = __float_as_uint(x);
    return (u + 0x7fffu + ((u >> 16) & 1u)) >> 16;
}

// ---- CSR build pass A: global bucket histogram (LDS-aggregated) ----
__global__ __launch_bounds__(256) void bucket_count(
    const int* __restrict__ dst, int E, unsigned* __restrict__ bhist, int NB)
{
    __shared__ unsigned lh[1024];
    for (int i = threadIdx.x; i < NB; i += 256) lh[i] = 0;
    __syncthreads();
    int stride = gridDim.x * blockDim.x;
    for (int e = blockIdx.x * blockDim.x + threadIdx.x; e < E; e += stride)
        atomicAdd(&lh[dst[e] >> NBSHIFT], 1u);
    __syncthreads();
    for (int i = threadIdx.x; i < NB; i += 256)
        if (lh[i]) atomicAdd(&bhist[i], lh[i]);
}

// ---- pass B0: exclusive scan of bucket sizes -> boff, init gcur ----
__global__ void bucket_scan(const unsigned* __restrict__ bhist, int* __restrict__ boff,
                            unsigned* __restrict__ gcur, int NB, int E)
{
    __shared__ unsigned s[1024];
    int i = threadIdx.x;
    unsigned x = (i < NB) ? bhist[i] : 0u;
    s[i] = x;
    __syncthreads();
    #pragma unroll
    for (int d = 1; d < 1024; d <<= 1) {
        unsigned t = (i >= d) ? s[i - d] : 0u;
        __syncthreads();
        s[i] += t;
        __syncthreads();
    }
    if (i < NB) { boff[i] = (int)(s[i] - x); gcur[i] = s[i] - x; }
    if (i == NB - 1) boff[NB] = (int)s[i];
}

// ---- pass B: scatter (dst,src) pairs into bucket-contiguous buf ----
__global__ __launch_bounds__(256) void bucket_scatter(
    const int* __restrict__ src, const int* __restrict__ dst, int E,
    unsigned* __restrict__ gcur, unsigned long long* __restrict__ buf, int NB)
{
    __shared__ unsigned lh[1024];
    __shared__ unsigned lbase[1024];
    for (int i = threadIdx.x; i < NB; i += 256) lh[i] = 0;
    __syncthreads();
    int tile = (E + gridDim.x - 1) / gridDim.x;
    int lo = blockIdx.x * tile, hi = min(E, lo + tile);
    for (int e = lo + threadIdx.x; e < hi; e += 256)
        atomicAdd(&lh[dst[e] >> NBSHIFT], 1u);
    __syncthreads();
    for (int i = threadIdx.x; i < NB; i += 256) {
        unsigned c = lh[i];
        lbase[i] = c ? atomicAdd(&gcur[i], c) : 0u;
        lh[i] = 0;
    }
    __syncthreads();
    for (int e = lo + threadIdx.x; e < hi; e += 256) {
        int d = dst[e];
        int b = d >> NBSHIFT;
        unsigned r = atomicAdd(&lh[b], 1u);
        buf[lbase[b] + r] = ((unsigned long long)(unsigned)d << 32) | (unsigned)src[e];
    }
}

// ---- pass C: per-bucket local CSR + off + dinv, coalesced output ----
__global__ __launch_bounds__(256) void bucket_csr(
    const unsigned long long* __restrict__ buf, const int* __restrict__ boff,
    int* __restrict__ csr, int* __restrict__ off, float* __restrict__ dinv,
    int N, int E)
{
    __shared__ unsigned hist[128];
    __shared__ unsigned incl[128];
    __shared__ unsigned cur[128];
    __shared__ int lcsr[CSR_CAP];
    const int b = blockIdx.x, tid = threadIdx.x;
    const int lo = boff[b], hi = boff[b + 1], cnt = hi - lo;
    const int nbase = b << NBSHIFT;
    const int nn = min(128, N - nbase);

    if (tid < 128) hist[tid] = 0;
    __syncthreads();
    for (int i = lo + tid; i < hi; i += 256)
        atomicAdd(&hist[(int)(buf[i] >> 32) - nbase], 1u);
    __syncthreads();
    if (tid < 128) incl[tid] = hist[tid];
    __syncthreads();
    #pragma unroll
    for (int d = 1; d < 128; d <<= 1) {
        unsigned t = (tid < 128 && tid >= d) ? incl[tid - d] : 0u;
        __syncthreads();
        if (tid < 128) incl[tid] += t;
        __syncthreads();
    }
    if (tid < 128) {
        unsigned e0 = incl[tid] - hist[tid];          // exclusive local offset
        cur[tid] = e0;
        if (tid < nn) {
            off[nbase + tid] = lo + (int)e0;
            dinv[nbase + tid] = rsqrtf((float)(hist[tid] + 1u));
        }
    }
    if (b == 0 && tid == 0) off[N] = E;
    __syncthreads();
    if (cnt <= CSR_CAP) {
        for (int i = lo + tid; i < hi; i += 256) {
            unsigned long long p = buf[i];
            int dl = (int)(p >> 32) - nbase;
            unsigned r = atomicAdd(&cur[dl], 1u);
            lcsr[r] = (int)(p & 0xffffffffu);
        }
        __syncthreads();
        for (int i = tid; i < cnt; i += 256) csr[lo + i] = lcsr[i];
    } else {                                          // never in practice; correct fallback
        for (int i = lo + tid; i < hi; i += 256) {
            unsigned long long p = buf[i];
            int dl = (int)(p >> 32) - nbase;
            unsigned r = atomicAdd(&cur[dl], 1u);
            csr[lo + (int)r] = (int)(p & 0xffffffffu);
        }
    }
}

// ---- transpose + hi/lo split:  W [K][N] f32  ->  hi/lo [N][K] bf16 ----
__global__ void tsplit(const float* __restrict__ W, __bf16* __restrict__ hi,
                       __bf16* __restrict__ lo, int K, int Nc) {
    int i = blockIdx.x * 256 + threadIdx.x;
    if (i >= K * Nc) return;
    int k = i / Nc, n = i % Nc;
    float f = W[i];
    __bf16 h = (__bf16)f;
    hi[(size_t)n * K + k] = h;
    lo[(size_t)n * K + k] = (__bf16)(f - (float)h);
}

// ---- layer-1 GEMM: C = bf16((X @ W1) * dinv[row]), 3-term split-bf16 ----
// 32-row blocks, 4 waves col-split, double-buffered LDS A (1 barrier per kk).
template <int K>
__global__ __launch_bounds__(256) void gemm1_mfma(
    const float* __restrict__ A, const __bf16* __restrict__ Bhi,
    const __bf16* __restrict__ Blo, const float* __restrict__ dinv,
    __bf16* __restrict__ C, int M)
{
    constexpr int LDA = 40;
    __shared__ __bf16 shi[2][32][LDA];
    __shared__ __bf16 slo[2][32][LDA];

    const int tid = threadIdx.x;
    const int lane = tid & 63;
    const int wave = tid >> 6;
    const int m0 = blockIdx.x * 32;
    const int col0 = wave * 32;
    const int lrow = lane & 15;
    const int lk = (lane >> 4) * 8;
    const int arow = tid >> 3;                     // 8 threads per row
    const int ac4 = (tid & 7) * 4;
    const float* aptr = A + (size_t)min(m0 + arow, M - 1) * K + ac4;

    f32x4 acc[2][2];
    #pragma unroll
    for (int r = 0; r < 2; ++r)
        #pragma unroll
        for (int c = 0; c < 2; ++c) acc[r][c] = (f32x4){0.f, 0.f, 0.f, 0.f};

    float4 f = *(const float4*)aptr;               // prefetch kk=0
    for (int kk = 0; kk < K; kk += 32) {
        const int cur = (kk >> 5) & 1;
        bf16x4 h, l;
        h[0] = (__bf16)f.x; l[0] = (__bf16)(f.x - (float)h[0]);
        h[1] = (__bf16)f.y; l[1] = (__bf16)(f.y - (float)h[1]);
        h[2] = (__bf16)f.z; l[2] = (__bf16)(f.z - (float)h[2]);
        h[3] = (__bf16)f.w; l[3] = (__bf16)(f.w - (float)h[3]);
        *(bf16x4*)&shi[cur][arow][ac4] = h;
        *(bf16x4*)&slo[cur][arow][ac4] = l;
        __syncthreads();
        if (kk + 32 < K) f = *(const float4*)(aptr + kk + 32);   // prefetch next

        bf16x8 ah[2], al[2];
        #pragma unroll
        for (int r = 0; r < 2; ++r) {
            ah[r] = *(const bf16x8*)&shi[cur][r * 16 + lrow][lk];
            al[r] = *(const bf16x8*)&slo[cur][r * 16 + lrow][lk];
        }
        #pragma unroll
        for (int c = 0; c < 2; ++c) {
            bf16x8 bh = *(const bf16x8*)(Bhi + (size_t)(col0 + c * 16 + lrow) * K + kk + lk);
            bf16x8 bl = *(const bf16x8*)(Blo + (size_t)(col0 + c * 16 + lrow) * K + kk + lk);
            #pragma unroll
            for (int r = 0; r < 2; ++r) {
                acc[r][c] = __builtin_amdgcn_mfma_f32_16x16x32_bf16(ah[r], bh, acc[r][c], 0, 0, 0);
                acc[r][c] = __builtin_amdgcn_mfma_f32_16x16x32_bf16(ah[r], bl, acc[r][c], 0, 0, 0);
                acc[r][c] = __builtin_amdgcn_mfma_f32_16x16x32_bf16(al[r], bh, acc[r][c], 0, 0, 0);
            }
        }
    }
    // C/D layout: col = lane&15, row = (lane>>4)*4 + j
    #pragma unroll
    for (int r = 0; r < 2; ++r) {
        #pragma unroll
        for (int j = 0; j < 4; ++j) {
            int m = m0 + r * 16 + (lane >> 4) * 4 + j;
            if (m >= M) continue;
            float dv = dinv[m];
            #pragma unroll
            for (int c = 0; c < 2; ++c)
                C[(size_t)m * 128 + col0 + c * 16 + lrow] = (__bf16)(acc[r][c][j] * dv);
        }
    }
}

// ---- layer-2 GEMM: C = bf16((h1 @ W2) * dinv[row]), A already bf16 ----
template <int K>
__global__ __launch_bounds__(256) void gemm2_mfma(
    const __bf16* __restrict__ A, const __bf16* __restrict__ Bhi,
    const __bf16* __restrict__ Blo, const float* __restrict__ dinv,
    __bf16* __restrict__ C, int M)
{
    const int lane = threadIdx.x & 63;
    const int wave = threadIdx.x >> 6;
    const int m0 = blockIdx.x * 64 + (wave >> 1) * 32;
    const int col0 = (wave & 1) * 32;
    const int lrow = lane & 15;
    const int lk = (lane >> 4) * 8;

    f32x4 acc[2][2];
    #pragma unroll
    for (int r = 0; r < 2; ++r)
        #pragma unroll
        for (int c = 0; c < 2; ++c) acc[r][c] = (f32x4){0.f, 0.f, 0.f, 0.f};

    #pragma unroll
    for (int kk = 0; kk < K; kk += 32) {
        bf16x8 ah[2];
        #pragma unroll
        for (int r = 0; r < 2; ++r) {
            int gr = m0 + r * 16 + lrow; if (gr >= M) gr = M - 1;
            ah[r] = *(const bf16x8*)(A + (size_t)gr * K + kk + lk);
        }
        #pragma unroll
        for (int c = 0; c < 2; ++c) {
            bf16x8 bh = *(const bf16x8*)(Bhi + (size_t)(col0 + c * 16 + lrow) * K + kk + lk);
            bf16x8 bl = *(const bf16x8*)(Blo + (size_t)(col0 + c * 16 + lrow) * K + kk + lk);
            #pragma unroll
            for (int r = 0; r < 2; ++r) {
                acc[r][c] = __builtin_amdgcn_mfma_f32_16x16x32_bf16(ah[r], bh, acc[r][c], 0, 0, 0);
                acc[r][c] = __builtin_amdgcn_mfma_f32_16x16x32_bf16(ah[r], bl, acc[r][c], 0, 0, 0);
            }
        }
    }
    #pragma unroll
    for (int r = 0; r < 2; ++r) {
        #pragma unroll
        for (int j = 0; j < 4; ++j) {
            int m = m0 + r * 16 + (lane >> 4) * 4 + j;
            if (m >= M) continue;
            float dv = dinv[m];
            #pragma unroll
            for (int c = 0; c < 2; ++c)
                C[(size_t)m * 64 + col0 + c * 16 + lrow] = (__bf16)(acc[r][c][j] * dv);
        }
    }
}

// ---- pull aggregation F=128 (bf16 in, bf16 out, relu), unroll x8 ----
__global__ __launch_bounds__(256) void agg128(
    const int* __restrict__ off, const int* __restrict__ csr,
    const unsigned* __restrict__ hs,      // bf16x2 rows: 64 dwords per node
    const float* __restrict__ dinv, const float* __restrict__ bias,
    unsigned* __restrict__ h1, int N)
{
    const int lane = threadIdx.x & 63;
    const int v = blockIdx.x * 4 + (threadIdx.x >> 6);
    if (v >= N) return;
    const int s0 = off[v], s1 = off[v + 1];
    float a0 = 0.f, a1 = 0.f;
    for (int e0 = s0; e0 < s1; e0 += 64) {
        int nid = (e0 + lane < s1) ? csr[e0 + lane] : 0;
        int cnt = min(64, s1 - e0);
        int j = 0;
        for (; j + 8 <= cnt; j += 8) {
            unsigned u[8];
            #pragma unroll
            for (int q = 0; q < 8; ++q) {
                int s = __shfl(nid, j + q);
                u[q] = hs[(size_t)s * 64 + lane];
            }
            #pragma unroll
            for (int q = 0; q < 8; ++q) {
                a0 += __uint_as_float(u[q] << 16);
                a1 += __uint_as_float(u[q] & 0xffff0000u);
            }
        }
        for (; j < cnt; ++j) {
            int s = __shfl(nid, j);
            unsigned u = hs[(size_t)s * 64 + lane];
            a0 += __uint_as_float(u << 16);
            a1 += __uint_as_float(u & 0xffff0000u);
        }
    }
    unsigned su = hs[(size_t)v * 64 + lane];
    const float dv = dinv[v];
    float r0 = (a0 + __uint_as_float(su << 16)) * dv + bias[lane * 2 + 0];
    float r1 = (a1 + __uint_as_float(su & 0xffff0000u)) * dv + bias[lane * 2 + 1];
    r0 = fmaxf(r0, 0.f);
    r1 = fmaxf(r1, 0.f);
    h1[(size_t)v * 64 + lane] = rne16(r0) | (rne16(r1) << 16);
}

// ---- pull aggregation F=64 (bf16 in, f32 out), unroll x8 ----
__global__ __launch_bounds__(256) void agg64(
    const int* __restrict__ off, const int* __restrict__ csr,
    const unsigned short* __restrict__ hs2, const float* __restrict__ dinv,
    const float* __restrict__ bias, float* __restrict__ out, int N)
{
    const int lane = threadIdx.x & 63;
    const int v = blockIdx.x * 4 + (threadIdx.x >> 6);
    if (v >= N) return;
    const int s0 = off[v], s1 = off[v + 1];
    float a0 = 0.f;
    for (int e0 = s0; e0 < s1; e0 += 64) {
        int nid = (e0 + lane < s1) ? csr[e0 + lane] : 0;
        int cnt = min(64, s1 - e0);
        int j = 0;
        for (; j + 8 <= cnt; j += 8) {
            unsigned short u[8];
            #pragma unroll
            for (int q = 0; q < 8; ++q) {
                int s = __shfl(nid, j + q);
                u[q] = hs2[(size_t)s * 64 + lane];
            }
            #pragma unroll
            for (int q = 0; q < 8; ++q)
                a0 += __uint_as_float((unsigned)u[q] << 16);
        }
        for (; j < cnt; ++j) {
            int s = __shfl(nid, j);
            a0 += __uint_as_float((unsigned)hs2[(size_t)s * 64 + lane] << 16);
        }
    }
    float self = __uint_as_float((unsigned)hs2[(size_t)v * 64 + lane] << 16);
    out[(size_t)v * 64 + lane] = (a0 + self) * dinv[v] + bias[lane];
}

extern "C" void kernel_launch(void* const* d_in, const int* in_sizes, int n_in,
                              void* d_out, int out_size, void* d_ws, size_t ws_size,
                              hipStream_t stream)
{
    const float* x  = (const float*)d_in[0];
    const int*   ei = (const int*)d_in[1];
    const float* W1 = (const float*)d_in[2];
    const float* b1 = (const float*)d_in[3];
    const float* W2 = (const float*)d_in[4];
    const float* b2 = (const float*)d_in[5];
    float* out = (float*)d_out;

    const int N = in_sizes[0] / 512;
    const int E = in_sizes[1] / 2;
    const int* src = ei;
    const int* dst = ei + E;
    const int NB = (N + 127) >> NBSHIFT;            // buckets of 128 nodes

    // ---- workspace layout (buf first: 8B alignment) ----
    unsigned long long* buf = (unsigned long long*)d_ws;   // E pairs
    unsigned* bhist    = (unsigned*)(buf + E);             // NB
    int*      boff     = (int*)(bhist + NB);               // NB+1
    unsigned* gcur     = (unsigned*)(boff + NB + 1);       // NB
    int*      off      = (int*)(gcur + NB);                // N+1
    float*    dinv     = (float*)(off + N + 1);            // N
    int*      csr      = (int*)(dinv + N);                 // E
    __bf16*   Bt1hi    = (__bf16*)(csr + E);               // 128*512
    __bf16*   Bt1lo    = Bt1hi + 128 * 512;
    __bf16*   Bt2hi    = Bt1lo + 128 * 512;                // 64*128
    __bf16*   Bt2lo    = Bt2hi + 64 * 128;
    __bf16*   hs       = Bt2lo + 64 * 128;                 // N*128 bf16
    __bf16*   h1       = hs + (size_t)N * 128;             // N*128 bf16
    __bf16*   hs2      = h1 + (size_t)N * 128;             // N*64  bf16

    hipMemsetAsync(bhist, 0, (size_t)NB * 4, stream);

    // CSR build (bucket sort by dst)
    bucket_count<<<dim3(512), 256, 0, stream>>>(dst, E, bhist, NB);
    bucket_scan<<<dim3(1), 1024, 0, stream>>>(bhist, boff, gcur, NB, E);
    bucket_scatter<<<dim3(512), 256, 0, stream>>>(src, dst, E, gcur, buf, NB);
    bucket_csr<<<dim3(NB), 256, 0, stream>>>(buf, boff, csr, off, dinv, N, E);

    tsplit<<<dim3((512 * 128 + 255) / 256), 256, 0, stream>>>(W1, Bt1hi, Bt1lo, 512, 128);
    tsplit<<<dim3((128 * 64 + 255) / 256), 256, 0, stream>>>(W2, Bt2hi, Bt2lo, 128, 64);

    // layer 1
    gemm1_mfma<512><<<dim3((N + 31) / 32), 256, 0, stream>>>(x, Bt1hi, Bt1lo, dinv, hs, N);
    agg128<<<dim3((N + 3) / 4), 256, 0, stream>>>(
        off, csr, (const unsigned*)hs, dinv, b1, (unsigned*)h1, N);

    // layer 2
    gemm2_mfma<128><<<dim3((N + 63) / 64), 256, 0, stream>>>(h1, Bt2hi, Bt2lo, dinv, hs2, N);
    agg64<<<dim3((N + 3) / 4), 256, 0, stream>>>(
        off, csr, (const unsigned short*)hs2, dinv, b2, out, N);
}

// Round 7
// 804.816 us; speedup vs baseline: 10.8627x; 1.0060x over previous
//
#include <hip/hip_runtime.h>
#include <hip/hip_bf16.h>

// ---------------------------------------------------------------------------
// GCN 2-layer, pull-mode CSR + bf16 messages + split-bf16 MFMA GEMMs.
//   out = Ahat * relu(Ahat * X * W1 + b1) * W2 + b2
// R7: gemm1 rebuilt barrier-free: full W1 hi/lo in LDS (132 KB, padded),
//     8-wave 128x128 blocks, pure-stream K-loop (3 barriers per block total).
// ---------------------------------------------------------------------------

typedef __bf16 bf16x8 __attribute__((ext_vector_type(8)));
typedef float  f32x4  __attribute__((ext_vector_type(4)));

#define NBSHIFT 7          // 128 nodes per bucket
#define CSR_CAP 8192       // max edges per bucket staged in LDS

__device__ inline unsigned rne16(float x) {        // f32 -> bf16 bits (RNE)
    unsigned u = __float_as_uint(x);
    return (u + 0x7fffu + ((u >> 16) & 1u)) >> 16;
}

__device__ inline void split8(const float4& f0, const float4& f1, bf16x8& h, bf16x8& l) {
    float v[8] = {f0.x, f0.y, f0.z, f0.w, f1.x, f1.y, f1.z, f1.w};
    #pragma unroll
    for (int j = 0; j < 8; ++j) {
        __bf16 hh = (__bf16)v[j];
        h[j] = hh;
        l[j] = (__bf16)(v[j] - (float)hh);
    }
}

// ---- CSR build pass A: global bucket histogram (LDS-aggregated) ----
__global__ __launch_bounds__(256) void bucket_count(
    const int* __restrict__ dst, int E, unsigned* __restrict__ bhist, int NB)
{
    __shared__ unsigned lh[1024];
    for (int i = threadIdx.x; i < NB; i += 256) lh[i] = 0;
    __syncthreads();
    int stride = gridDim.x * blockDim.x;
    for (int e = blockIdx.x * blockDim.x + threadIdx.x; e < E; e += stride)
        atomicAdd(&lh[dst[e] >> NBSHIFT], 1u);
    __syncthreads();
    for (int i = threadIdx.x; i < NB; i += 256)
        if (lh[i]) atomicAdd(&bhist[i], lh[i]);
}

// ---- pass B0: exclusive scan of bucket sizes -> boff, init gcur ----
__global__ void bucket_scan(const unsigned* __restrict__ bhist, int* __restrict__ boff,
                            unsigned* __restrict__ gcur, int NB, int E)
{
    __shared__ unsigned s[1024];
    int i = threadIdx.x;
    unsigned x = (i < NB) ? bhist[i] : 0u;
    s[i] = x;
    __syncthreads();
    #pragma unroll
    for (int d = 1; d < 1024; d <<= 1) {
        unsigned t = (i >= d) ? s[i - d] : 0u;
        __syncthreads();
        s[i] += t;
        __syncthreads();
    }
    if (i < NB) { boff[i] = (int)(s[i] - x); gcur[i] = s[i] - x; }
    if (i == NB - 1) boff[NB] = (int)s[i];
}

// ---- pass B: scatter (dst,src) pairs into bucket-contiguous buf ----
__global__ __launch_bounds__(256) void bucket_scatter(
    const int* __restrict__ src, const int* __restrict__ dst, int E,
    unsigned* __restrict__ gcur, unsigned long long* __restrict__ buf, int NB)
{
    __shared__ unsigned lh[1024];
    __shared__ unsigned lbase[1024];
    for (int i = threadIdx.x; i < NB; i += 256) lh[i] = 0;
    __syncthreads();
    int tile = (E + gridDim.x - 1) / gridDim.x;
    int lo = blockIdx.x * tile, hi = min(E, lo + tile);
    for (int e = lo + threadIdx.x; e < hi; e += 256)
        atomicAdd(&lh[dst[e] >> NBSHIFT], 1u);
    __syncthreads();
    for (int i = threadIdx.x; i < NB; i += 256) {
        unsigned c = lh[i];
        lbase[i] = c ? atomicAdd(&gcur[i], c) : 0u;
        lh[i] = 0;
    }
    __syncthreads();
    for (int e = lo + threadIdx.x; e < hi; e += 256) {
        int d = dst[e];
        int b = d >> NBSHIFT;
        unsigned r = atomicAdd(&lh[b], 1u);
        buf[lbase[b] + r] = ((unsigned long long)(unsigned)d << 32) | (unsigned)src[e];
    }
}

// ---- pass C: per-bucket local CSR + off + dinv, coalesced output ----
__global__ __launch_bounds__(256) void bucket_csr(
    const unsigned long long* __restrict__ buf, const int* __restrict__ boff,
    int* __restrict__ csr, int* __restrict__ off, float* __restrict__ dinv,
    int N, int E)
{
    __shared__ unsigned hist[128];
    __shared__ unsigned incl[128];
    __shared__ unsigned cur[128];
    __shared__ int lcsr[CSR_CAP];
    const int b = blockIdx.x, tid = threadIdx.x;
    const int lo = boff[b], hi = boff[b + 1], cnt = hi - lo;
    const int nbase = b << NBSHIFT;
    const int nn = min(128, N - nbase);

    if (tid < 128) hist[tid] = 0;
    __syncthreads();
    for (int i = lo + tid; i < hi; i += 256)
        atomicAdd(&hist[(int)(buf[i] >> 32) - nbase], 1u);
    __syncthreads();
    if (tid < 128) incl[tid] = hist[tid];
    __syncthreads();
    #pragma unroll
    for (int d = 1; d < 128; d <<= 1) {
        unsigned t = (tid < 128 && tid >= d) ? incl[tid - d] : 0u;
        __syncthreads();
        if (tid < 128) incl[tid] += t;
        __syncthreads();
    }
    if (tid < 128) {
        unsigned e0 = incl[tid] - hist[tid];
        cur[tid] = e0;
        if (tid < nn) {
            off[nbase + tid] = lo + (int)e0;
            dinv[nbase + tid] = rsqrtf((float)(hist[tid] + 1u));
        }
    }
    if (b == 0 && tid == 0) off[N] = E;
    __syncthreads();
    if (cnt <= CSR_CAP) {
        for (int i = lo + tid; i < hi; i += 256) {
            unsigned long long p = buf[i];
            int dl = (int)(p >> 32) - nbase;
            unsigned r = atomicAdd(&cur[dl], 1u);
            lcsr[r] = (int)(p & 0xffffffffu);
        }
        __syncthreads();
        for (int i = tid; i < cnt; i += 256) csr[lo + i] = lcsr[i];
    } else {
        for (int i = lo + tid; i < hi; i += 256) {
            unsigned long long p = buf[i];
            int dl = (int)(p >> 32) - nbase;
            unsigned r = atomicAdd(&cur[dl], 1u);
            csr[lo + (int)r] = (int)(p & 0xffffffffu);
        }
    }
}

// ---- transpose + hi/lo split:  W [K][N] f32  ->  hi/lo [N][K] bf16 ----
__global__ void tsplit(const float* __restrict__ W, __bf16* __restrict__ hi,
                       __bf16* __restrict__ lo, int K, int Nc) {
    int i = blockIdx.x * 256 + threadIdx.x;
    if (i >= K * Nc) return;
    int k = i / Nc, n = i % Nc;
    float f = W[i];
    __bf16 h = (__bf16)f;
    hi[(size_t)n * K + k] = h;
    lo[(size_t)n * K + k] = (__bf16)(f - (float)h);
}

// ---- layer-1 GEMM: C = bf16((X @ W1) * dinv[row]), 3-term split-bf16 ----
// Barrier-free K-loop: full W1 hi/lo in padded LDS (132 KB), 8 waves,
// block = 128 rows x 128 cols, wave = 64 rows x 32 cols (r=4, c=2).
// LDS staged in two K-halves (3 barriers per block total).
__global__ __launch_bounds__(512, 2) void gemm1_mfma(
    const float* __restrict__ A, const __bf16* __restrict__ Bhi,
    const __bf16* __restrict__ Blo, const float* __restrict__ dinv,
    __bf16* __restrict__ C, int M)
{
    constexpr int LDC = 264;                 // bf16 elems per col (528B: 2-way banks)
    __shared__ __bf16 sb[2][128][LDC];       // [hi/lo][col][k-within-half]  132 KB

    const int tid = threadIdx.x;
    const int lane = tid & 63;
    const int w = tid >> 6;
    const int rg = w >> 2, cg = w & 3;
    const int m0 = blockIdx.x * 128 + rg * 64;
    const int col0 = cg * 32;
    const int lrow = lane & 15;
    const int lk = (lane >> 4) * 8;

    // A row base pointers (clamped for tail block)
    const float* aptr[4];
    #pragma unroll
    for (int rt = 0; rt < 4; ++rt) {
        int r = m0 + rt * 16 + lrow;
        if (r >= M) r = M - 1;
        aptr[rt] = A + (size_t)r * 512 + lk;
    }

    f32x4 acc[4][2];
    #pragma unroll
    for (int rt = 0; rt < 4; ++rt)
        #pragma unroll
        for (int c = 0; c < 2; ++c) acc[rt][c] = (f32x4){0.f, 0.f, 0.f, 0.f};

    float4 fc[4][2], fn[4][2];
    #pragma unroll
    for (int rt = 0; rt < 4; ++rt) {
        fc[rt][0] = *(const float4*)(aptr[rt] + 0);
        fc[rt][1] = *(const float4*)(aptr[rt] + 4);
    }

    #pragma unroll 1
    for (int h = 0; h < 2; ++h) {
        if (h) __syncthreads();              // all waves done reading half0
        // stage W1 K-half h: 2 arrays x 128 cols x 512B, 16B per thread-iter
        for (int i = tid; i < 8192; i += 512) {
            int a = i >> 12, rem = i & 4095, col = rem >> 5, seg = rem & 31;
            const __bf16* g = (a ? Blo : Bhi) + (size_t)col * 512 + h * 256 + seg * 8;
            *(bf16x8*)&sb[a][col][seg * 8] = *(const bf16x8*)g;
        }
        __syncthreads();

        #pragma unroll
        for (int s = 0; s < 8; ++s) {
            const int kk = h * 256 + s * 32;
            if (kk + 32 < 512) {             // prefetch next K-step's A
                #pragma unroll
                for (int rt = 0; rt < 4; ++rt) {
                    fn[rt][0] = *(const float4*)(aptr[rt] + kk + 32);
                    fn[rt][1] = *(const float4*)(aptr[rt] + kk + 36);
                }
            }
            bf16x8 ah[4], al[4];
            #pragma unroll
            for (int rt = 0; rt < 4; ++rt) split8(fc[rt][0], fc[rt][1], ah[rt], al[rt]);

            #pragma unroll
            for (int c = 0; c < 2; ++c) {
                bf16x8 bh = *(const bf16x8*)&sb[0][col0 + c * 16 + lrow][s * 32 + lk];
                bf16x8 bl = *(const bf16x8*)&sb[1][col0 + c * 16 + lrow][s * 32 + lk];
                #pragma unroll
                for (int rt = 0; rt < 4; ++rt) {
                    acc[rt][c] = __builtin_amdgcn_mfma_f32_16x16x32_bf16(ah[rt], bh, acc[rt][c], 0, 0, 0);
                    acc[rt][c] = __builtin_amdgcn_mfma_f32_16x16x32_bf16(ah[rt], bl, acc[rt][c], 0, 0, 0);
                    acc[rt][c] = __builtin_amdgcn_mfma_f32_16x16x32_bf16(al[rt], bh, acc[rt][c], 0, 0, 0);
                }
            }
            #pragma unroll
            for (int rt = 0; rt < 4; ++rt) {
                fc[rt][0] = fn[rt][0];
                fc[rt][1] = fn[rt][1];
            }
        }
    }

    // C/D layout: col = lane&15, row = (lane>>4)*4 + j
    #pragma unroll
    for (int rt = 0; rt < 4; ++rt) {
        #pragma unroll
        for (int j = 0; j < 4; ++j) {
            int m = m0 + rt * 16 + (lane >> 4) * 4 + j;
            if (m >= M) continue;
            float dv = dinv[m];
            #pragma unroll
            for (int c = 0; c < 2; ++c)
                C[(size_t)m * 128 + col0 + c * 16 + lrow] = (__bf16)(acc[rt][c][j] * dv);
        }
    }
}

// ---- layer-2 GEMM: C = bf16((h1 @ W2) * dinv[row]), A already bf16 ----
template <int K>
__global__ __launch_bounds__(256) void gemm2_mfma(
    const __bf16* __restrict__ A, const __bf16* __restrict__ Bhi,
    const __bf16* __restrict__ Blo, const float* __restrict__ dinv,
    __bf16* __restrict__ C, int M)
{
    const int lane = threadIdx.x & 63;
    const int wave = threadIdx.x >> 6;
    const int m0 = blockIdx.x * 64 + (wave >> 1) * 32;
    const int col0 = (wave & 1) * 32;
    const int lrow = lane & 15;
    const int lk = (lane >> 4) * 8;

    f32x4 acc[2][2];
    #pragma unroll
    for (int r = 0; r < 2; ++r)
        #pragma unroll
        for (int c = 0; c < 2; ++c) acc[r][c] = (f32x4){0.f, 0.f, 0.f, 0.f};

    #pragma unroll
    for (int kk = 0; kk < K; kk += 32) {
        bf16x8 ah[2];
        #pragma unroll
        for (int r = 0; r < 2; ++r) {
            int gr = m0 + r * 16 + lrow; if (gr >= M) gr = M - 1;
            ah[r] = *(const bf16x8*)(A + (size_t)gr * K + kk + lk);
        }
        #pragma unroll
        for (int c = 0; c < 2; ++c) {
            bf16x8 bh = *(const bf16x8*)(Bhi + (size_t)(col0 + c * 16 + lrow) * K + kk + lk);
            bf16x8 bl = *(const bf16x8*)(Blo + (size_t)(col0 + c * 16 + lrow) * K + kk + lk);
            #pragma unroll
            for (int r = 0; r < 2; ++r) {
                acc[r][c] = __builtin_amdgcn_mfma_f32_16x16x32_bf16(ah[r], bh, acc[r][c], 0, 0, 0);
                acc[r][c] = __builtin_amdgcn_mfma_f32_16x16x32_bf16(ah[r], bl, acc[r][c], 0, 0, 0);
            }
        }
    }
    #pragma unroll
    for (int r = 0; r < 2; ++r) {
        #pragma unroll
        for (int j = 0; j < 4; ++j) {
            int m = m0 + r * 16 + (lane >> 4) * 4 + j;
            if (m >= M) continue;
            float dv = dinv[m];
            #pragma unroll
            for (int c = 0; c < 2; ++c)
                C[(size_t)m * 64 + col0 + c * 16 + lrow] = (__bf16)(acc[r][c][j] * dv);
        }
    }
}

// ---- pull aggregation F=128 (bf16 in, bf16 out, relu), unroll x8 ----
__global__ __launch_bounds__(256) void agg128(
    const int* __restrict__ off, const int* __restrict__ csr,
    const unsigned* __restrict__ hs,      // bf16x2 rows: 64 dwords per node
    const float* __restrict__ dinv, const float* __restrict__ bias,
    unsigned* __restrict__ h1, int N)
{
    const int lane = threadIdx.x & 63;
    const int v = blockIdx.x * 4 + (threadIdx.x >> 6);
    if (v >= N) return;
    const int s0 = off[v], s1 = off[v + 1];
    float a0 = 0.f, a1 = 0.f;
    for (int e0 = s0; e0 < s1; e0 += 64) {
        int nid = (e0 + lane < s1) ? csr[e0 + lane] : 0;
        int cnt = min(64, s1 - e0);
        int j = 0;
        for (; j + 8 <= cnt; j += 8) {
            unsigned u[8];
            #pragma unroll
            for (int q = 0; q < 8; ++q) {
                int s = __shfl(nid, j + q);
                u[q] = hs[(size_t)s * 64 + lane];
            }
            #pragma unroll
            for (int q = 0; q < 8; ++q) {
                a0 += __uint_as_float(u[q] << 16);
                a1 += __uint_as_float(u[q] & 0xffff0000u);
            }
        }
        for (; j < cnt; ++j) {
            int s = __shfl(nid, j);
            unsigned u = hs[(size_t)s * 64 + lane];
            a0 += __uint_as_float(u << 16);
            a1 += __uint_as_float(u & 0xffff0000u);
        }
    }
    unsigned su = hs[(size_t)v * 64 + lane];
    const float dv = dinv[v];
    float r0 = (a0 + __uint_as_float(su << 16)) * dv + bias[lane * 2 + 0];
    float r1 = (a1 + __uint_as_float(su & 0xffff0000u)) * dv + bias[lane * 2 + 1];
    r0 = fmaxf(r0, 0.f);
    r1 = fmaxf(r1, 0.f);
    h1[(size_t)v * 64 + lane] = rne16(r0) | (rne16(r1) << 16);
}

// ---- pull aggregation F=64 (bf16 in, f32 out), unroll x8 ----
__global__ __launch_bounds__(256) void agg64(
    const int* __restrict__ off, const int* __restrict__ csr,
    const unsigned short* __restrict__ hs2, const float* __restrict__ dinv,
    const float* __restrict__ bias, float* __restrict__ out, int N)
{
    const int lane = threadIdx.x & 63;
    const int v = blockIdx.x * 4 + (threadIdx.x >> 6);
    if (v >= N) return;
    const int s0 = off[v], s1 = off[v + 1];
    float a0 = 0.f;
    for (int e0 = s0; e0 < s1; e0 += 64) {
        int nid = (e0 + lane < s1) ? csr[e0 + lane] : 0;
        int cnt = min(64, s1 - e0);
        int j = 0;
        for (; j + 8 <= cnt; j += 8) {
            unsigned short u[8];
            #pragma unroll
            for (int q = 0; q < 8; ++q) {
                int s = __shfl(nid, j + q);
                u[q] = hs2[(size_t)s * 64 + lane];
            }
            #pragma unroll
            for (int q = 0; q < 8; ++q)
                a0 += __uint_as_float((unsigned)u[q] << 16);
        }
        for (; j < cnt; ++j) {
            int s = __shfl(nid, j);
            a0 += __uint_as_float((unsigned)hs2[(size_t)s * 64 + lane] << 16);
        }
    }
    float self = __uint_as_float((unsigned)hs2[(size_t)v * 64 + lane] << 16);
    out[(size_t)v * 64 + lane] = (a0 + self) * dinv[v] + bias[lane];
}

extern "C" void kernel_launch(void* const* d_in, const int* in_sizes, int n_in,
                              void* d_out, int out_size, void* d_ws, size_t ws_size,
                              hipStream_t stream)
{
    const float* x  = (const float*)d_in[0];
    const int*   ei = (const int*)d_in[1];
    const float* W1 = (const float*)d_in[2];
    const float* b1 = (const float*)d_in[3];
    const float* W2 = (const float*)d_in[4];
    const float* b2 = (const float*)d_in[5];
    float* out = (float*)d_out;

    const int N = in_sizes[0] / 512;
    const int E = in_sizes[1] / 2;
    const int* src = ei;
    const int* dst = ei + E;
    const int NB = (N + 127) >> NBSHIFT;

    // ---- workspace layout (buf first: 8B alignment) ----
    unsigned long long* buf = (unsigned long long*)d_ws;   // E pairs
    unsigned* bhist    = (unsigned*)(buf + E);             // NB
    int*      boff     = (int*)(bhist + NB);               // NB+1
    unsigned* gcur     = (unsigned*)(boff + NB + 1);       // NB
    int*      off      = (int*)(gcur + NB);                // N+1
    float*    dinv     = (float*)(off + N + 1);            // N
    int*      csr      = (int*)(dinv + N);                 // E
    __bf16*   Bt1hi    = (__bf16*)(csr + E);               // 128*512
    __bf16*   Bt1lo    = Bt1hi + 128 * 512;
    __bf16*   Bt2hi    = Bt1lo + 128 * 512;                // 64*128
    __bf16*   Bt2lo    = Bt2hi + 64 * 128;
    __bf16*   hs       = Bt2lo + 64 * 128;                 // N*128 bf16
    __bf16*   h1       = hs + (size_t)N * 128;             // N*128 bf16
    __bf16*   hs2      = h1 + (size_t)N * 128;             // N*64  bf16

    hipMemsetAsync(bhist, 0, (size_t)NB * 4, stream);

    // CSR build (bucket sort by dst)
    bucket_count<<<dim3(512), 256, 0, stream>>>(dst, E, bhist, NB);
    bucket_scan<<<dim3(1), 1024, 0, stream>>>(bhist, boff, gcur, NB, E);
    bucket_scatter<<<dim3(512), 256, 0, stream>>>(src, dst, E, gcur, buf, NB);
    bucket_csr<<<dim3(NB), 256, 0, stream>>>(buf, boff, csr, off, dinv, N, E);

    tsplit<<<dim3((512 * 128 + 255) / 256), 256, 0, stream>>>(W1, Bt1hi, Bt1lo, 512, 128);
    tsplit<<<dim3((128 * 64 + 255) / 256), 256, 0, stream>>>(W2, Bt2hi, Bt2lo, 128, 64);

    // layer 1
    gemm1_mfma<<<dim3((N + 127) / 128), 512, 0, stream>>>(x, Bt1hi, Bt1lo, dinv, hs, N);
    agg128<<<dim3((N + 3) / 4), 256, 0, stream>>>(
        off, csr, (const unsigned*)hs, dinv, b1, (unsigned*)h1, N);

    // layer 2
    gemm2_mfma<128><<<dim3((N + 63) / 64), 256, 0, stream>>>(h1, Bt2hi, Bt2lo, dinv, hs2, N);
    agg64<<<dim3((N + 3) / 4), 256, 0, stream>>>(
        off, csr, (const unsigned short*)hs2, dinv, b2, out, N);
}